// Round 4
// baseline (2810.053 us; speedup 1.0000x reference)
//
#include <hip/hip_runtime.h>

typedef unsigned short u16;
typedef __attribute__((ext_vector_type(8))) short short8;
typedef __attribute__((ext_vector_type(4))) float floatx4;

#define B_   32
#define L_   128
#define D_   300
#define DP_  320
#define H_   1024
#define G4_  4096
#define K3_  3072
#define NROUNDS 40        // fallback path only (f32 weights)

#define MO_MAXLEV 0
#define MO_ROOT   8
#define MO_LSTART 64
#define MO_LCOUNT 256
#define MO_FLG    448     // 64 scan barrier flags
#define MO_NODES  512
#define MO_CNT    4608    // 160 per-level arrival counters (k_forest)
#define SPIN_CAP  500000
#define SPIN_CAP2 200000

#define FGRID 512         // k_forest blocks: FGRP tile-groups x 64 col-slices
#define FGRP  8           // MUST keep all FGRID blocks co-resident (barrier!)

#define MFMA(a,b,c) __builtin_amdgcn_mfma_f32_16x16x32_bf16((a),(b),(c),0,0,0)

__device__ inline float b2f(u16 u){ union { unsigned int i; float f; } v; v.i = ((unsigned int)u) << 16; return v.f; }
__device__ inline u16 f2b(float f){ union { float f; unsigned int i; } v; v.f = f; unsigned int r = v.i + 0x7FFFu + ((v.i >> 16) & 1u); return (u16)(r >> 16); }
__device__ inline float h2f(u16 u){ union { _Float16 h; u16 s; } v; v.s = u; return (float)v.h; }
__device__ inline u16 f2h(float f){ union { _Float16 h; u16 s; } v; v.h = (_Float16)f; return v.s; }
__device__ inline float sigf(float x){ return 1.f / (1.f + __expf(-x)); }
__device__ inline float tanh_(float x){ return 1.f - 2.f / (__expf(2.f * x) + 1.f); }
__device__ inline short8 cvt8(const float* p){
  floatx4 a = *(const floatx4*)p, b = *(const floatx4*)(p + 4);
  short8 r;
  r[0]=(short)f2b(a[0]); r[1]=(short)f2b(a[1]); r[2]=(short)f2b(a[2]); r[3]=(short)f2b(a[3]);
  r[4]=(short)f2b(b[0]); r[5]=(short)f2b(b[1]); r[6]=(short)f2b(b[2]); r[7]=(short)f2b(b[3]);
  return r;
}

// ---------------- K_init: pad+convert inputs, zero state, optional Wcomp cvt -
__global__ void k_init(const float* __restrict__ emb, const float* __restrict__ Wih,
                       const float* __restrict__ Wcomp,
                       u16* __restrict__ embP, u16* __restrict__ WihP,
                       u16* __restrict__ WcompB,            // may be null
                       u16* __restrict__ nodeH, float* __restrict__ nodeC, int* meta)
{
  const int gtid = blockIdx.x * 256 + threadIdx.x;
  const int nT = 2048 * 256;
  if (gtid < 64) meta[MO_FLG + gtid] = 0;               // scan barrier flags
  for (int i = gtid; i < B_ * H_; i += nT) {            // zero row (leaf idx 128)
    int b = i >> 10, c = i & (H_ - 1);
    nodeH[(size_t)(b * 129 + 128) * H_ + c] = 0;
    nodeC[(size_t)(b * 129 + 128) * H_ + c] = 0.f;
  }
  for (int i = gtid; i < B_ * L_ * DP_; i += nT) {      // pad K 300 -> 320
    int r = i / DP_, k = i - r * DP_;
    embP[i] = (k < D_) ? f2b(emb[(size_t)r * D_ + k]) : (u16)0;
  }
  for (int i = gtid; i < G4_ * DP_; i += nT) {
    int r = i / DP_, k = i - r * DP_;
    WihP[i] = (k < D_) ? f2b(Wih[(size_t)r * D_ + k]) : (u16)0;
  }
  if (WcompB) {                                         // 6144x3072 f32 -> bf16
    for (int c = gtid; c < (6 * H_ * K3_) / 8; c += nT)
      *(short8*)(WcompB + (size_t)c * 8) = cvt8(Wcomp + (size_t)c * 8);
  }
}

// ---------------- K_xg: Xg[b*128+t][4096] = emb @ Wih^T + b_ih + b_hh (fp16) -
__global__ __launch_bounds__(256) void k_xg(const u16* __restrict__ embP,
    const u16* __restrict__ WihP, const float* __restrict__ bih,
    const float* __restrict__ bhh, u16* __restrict__ Xg)
{
  const int lane = threadIdx.x & 63, wave = threadIdx.x >> 6;
  const int l15 = lane & 15, quad = lane >> 4;
  const int gw = blockIdx.x * 4 + wave;
  for (int st = gw; st < 128 * 128; st += 2048 * 4) {
    int tm = st >> 7, tn = st & 127;
    int m0 = tm * 32, n0 = tn * 32;
    floatx4 acc[2][2] = {};
    for (int kc = 0; kc < DP_ / 32; ++kc) {
      int ko = kc * 32 + quad * 8;
      short8 a0 = *(const short8*)(embP + (size_t)(m0 + l15) * DP_ + ko);
      short8 a1 = *(const short8*)(embP + (size_t)(m0 + 16 + l15) * DP_ + ko);
      short8 b0 = *(const short8*)(WihP + (size_t)(n0 + l15) * DP_ + ko);
      short8 b1 = *(const short8*)(WihP + (size_t)(n0 + 16 + l15) * DP_ + ko);
      acc[0][0] = MFMA(a0, b0, acc[0][0]);
      acc[0][1] = MFMA(a0, b1, acc[0][1]);
      acc[1][0] = MFMA(a1, b0, acc[1][0]);
      acc[1][1] = MFMA(a1, b1, acc[1][1]);
    }
    for (int mi = 0; mi < 2; ++mi)
      for (int ni = 0; ni < 2; ++ni)
        for (int r = 0; r < 4; ++r) {
          int m = m0 + mi * 16 + quad * 4 + r;
          int n = n0 + ni * 16 + l15;
          float v = acc[mi][ni][r] + bih[n] + bhh[n];
          Xg[(size_t)m * G4_ + n] = f2h(v);
        }
  }
}

// ---------------- K_scan: fence-free; B slice in TRUE VGPRs (full unroll) ----
#define SCAN_LDS (65536 + 4*32*17*4)
__global__ __launch_bounds__(256, 1) void k_scan(const float* __restrict__ Whh,
    const u16* __restrict__ Xg, u16* __restrict__ nodeH,
    float* __restrict__ nodeC, u16* __restrict__ hEx, int* meta)
{
  extern __shared__ char smem[];
  u16*   hst = (u16*)smem;                    // [32][1024] bf16, XOR-swizzled
  float* sG  = (float*)(smem + 65536);        // [4][32][17] gate pre-acts
  const int tid = threadIdx.x;
  const int g = tid >> 6, lane = tid & 63;
  const int l15 = lane & 15, quad = lane >> 4;
  const int n16 = blockIdx.x;
  int* flags = meta + MO_FLG;

  // B (gate g, cols n16*16..+16, all k) -> 128 persistent VGPRs (f32 -> bf16)
  short8 bf[32];
#pragma unroll
  for (int kc = 0; kc < 32; ++kc)
    bf[kc] = cvt8(Whh + ((size_t)(g * 1024 + n16 * 16 + l15)) * 1024 + kc * 32 + quad * 8);

  const int cb = g * 8 + (lane & 7);          // cell batch
  const int cp = lane >> 3;                   // cell col-pair
  const int c0 = n16 * 16 + cp * 2;

  float cst0 = 0.f, cst1 = 0.f;
  for (int t = 0; t < L_; ++t) {
    // prefetch this step's Xg gate inputs (independent of h(t-1))
    float xv[4][2];
    {
      const u16* xr = Xg + (size_t)(cb * 128 + t) * G4_;
#pragma unroll
      for (int gg = 0; gg < 4; ++gg)
#pragma unroll
        for (int u = 0; u < 2; ++u)
          xv[gg][u] = h2f(xr[gg * 1024 + c0 + u]);
    }
    floatx4 acc[2] = {};
    if (t > 0) {
      // stage h(t-1): 8192 u64 agent-coherent loads -> swizzled LDS
      const unsigned long long* src =
          (const unsigned long long*)(hEx + ((t - 1) & 1) * (B_ * H_));
#pragma unroll
      for (int ch = 0; ch < 2; ++ch) {
        unsigned long long tmp[16];
#pragma unroll
        for (int q = 0; q < 16; ++q)
          tmp[q] = __hip_atomic_load(src + (ch * 16 + q) * 256 + tid,
                                     __ATOMIC_RELAXED, __HIP_MEMORY_SCOPE_AGENT);
#pragma unroll
        for (int q = 0; q < 16; ++q) {
          int idx = (ch * 16 + q) * 256 + tid;
          int b = idx >> 8, g8 = idx & 255, gr = g8 >> 1;
          *(unsigned long long*)(hst + (b << 10) + ((gr ^ (b & 7)) << 3) + (g8 & 1) * 4) = tmp[q];
        }
      }
      __syncthreads();
#pragma unroll
      for (int kc = 0; kc < 32; ++kc) {       // FULL unroll -> bf[] stays in VGPRs
        int gr = (kc * 4 + quad) ^ (l15 & 7);
        short8 a0 = *(const short8*)(hst + (l15 << 10) + (gr << 3));
        short8 a1 = *(const short8*)(hst + ((16 + l15) << 10) + (gr << 3));
        acc[0] = MFMA(a0, bf[kc], acc[0]);
        acc[1] = MFMA(a1, bf[kc], acc[1]);
      }
    }
#pragma unroll
    for (int mt = 0; mt < 2; ++mt)
#pragma unroll
      for (int r = 0; r < 4; ++r)
        sG[(g * 32 + mt * 16 + quad * 4 + r) * 17 + l15] = acc[mt][r];
    __syncthreads();
    // cell update
    {
      float cc[2] = { cst0, cst1 };
      float hh[2];
#pragma unroll
      for (int u = 0; u < 2; ++u) {
        int col = cp * 2 + u;
        float iv = sG[(0 * 32 + cb) * 17 + col] + xv[0][u];
        float fv = sG[(1 * 32 + cb) * 17 + col] + xv[1][u];
        float gv = sG[(2 * 32 + cb) * 17 + col] + xv[2][u];
        float ov = sG[(3 * 32 + cb) * 17 + col] + xv[3][u];
        float c = sigf(fv) * cc[u] + sigf(iv) * tanh_(gv);
        float h = sigf(ov) * tanh_(c);
        cc[u] = c; hh[u] = h;
      }
      cst0 = cc[0]; cst1 = cc[1];
      unsigned pack = (unsigned)f2b(hh[0]) | ((unsigned)f2b(hh[1]) << 16);
      __hip_atomic_store((unsigned*)(hEx + (t & 1) * (B_ * H_)) + (cb << 9) + (c0 >> 1),
                         pack, __ATOMIC_RELAXED, __HIP_MEMORY_SCOPE_AGENT);
      *(unsigned*)(nodeH + (size_t)(cb * 129 + t) * H_ + c0) = pack;   // leaf archive
      *(float2*)(nodeC + (size_t)(cb * 129 + t) * H_ + c0) = make_float2(cc[0], cc[1]);
    }
    __syncthreads();   // drains vmcnt for all waves before flag release
    if (tid == 0)
      __hip_atomic_store(&flags[n16], t + 1, __ATOMIC_RELAXED, __HIP_MEMORY_SCOPE_AGENT);
    if (g == 0) {      // wave 0: one flag per lane, ballot across 64 blocks
      int it = 0;
      for (;;) {
        int v = __hip_atomic_load(&flags[lane], __ATOMIC_RELAXED, __HIP_MEMORY_SCOPE_AGENT);
        if (__all(v >= t + 1) || ++it >= SPIN_CAP) break;
        __builtin_amdgcn_s_sleep(1);
      }
    }
    __syncthreads();
  }
}

// ---------------- K_tree: O(n) Cartesian trees + O(n) level schedule ---------
__global__ void k_tree(const int* __restrict__ words, const int* __restrict__ lens,
                       int* meta)
{
  const int tid = threadIdx.x;
  __shared__ u16 sD[B_][L_];
  __shared__ short sL[B_][L_], sR[B_][L_];     // raw child indices, -1 = none
  __shared__ short sS[B_][130];                // stack (build, then preorder)
  __shared__ short sO[B_][L_];                 // preorder sequence
  __shared__ unsigned char sLev[B_][L_];       // height; 0 = Cartesian leaf
  __shared__ int sHist[132], sCur[132], sMaxLev;
  for (int i = tid; i < 132; i += 256) { sHist[i] = 0; sCur[i] = 0; }
  if (tid == 0) sMaxLev = 1;
  for (int i = tid; i < 160; i += 256) meta[MO_CNT + i] = 0;   // forest counters
  for (int i = tid; i < B_ * L_; i += 256) {   // parallel, coalesced init
    int b = i >> 7, t = i & 127;
    sD[b][t] = (u16)(words[i] % 1000);
    sL[b][t] = -1; sR[b][t] = -1; sLev[b][t] = 0;
  }
  __syncthreads();
  if (tid < B_) {
    const int b = tid;
    int len = lens[b];
    if (len < 2) len = 2;
    if (len > 128) len = 128;
    // --- 1. monotone-stack Cartesian min-tree (ties: leftmost is ancestor) ---
    int sp = 0;
    for (int i = 0; i < len; ++i) {
      int v = sD[b][i];
      int last = -1;
      while (sp > 0) {
        int top = sS[b][sp - 1];
        if ((int)sD[b][top] > v) { last = top; --sp; } else break;
      }
      sL[b][i] = (short)last;                  // last popped = left child of i
      if (sp > 0) sR[b][sS[b][sp - 1]] = (short)i; // i = (current) right child
      sS[b][sp++] = (short)i;
    }
    const int root = sS[b][0];                 // stack bottom = global min
    meta[MO_ROOT + b] = root;
    // --- 2a. preorder via explicit stack ---
    int cnt = 0, tp = 0;
    sS[b][tp++] = (short)root;
    while (tp > 0) {
      int p = sS[b][--tp];
      sO[b][cnt++] = (short)p;
      int l = sL[b][p], r = sR[b][p];
      if (l >= 0) sS[b][tp++] = (short)l;
      if (r >= 0) sS[b][tp++] = (short)r;
    }
    // --- 2b. reverse preorder: children processed before parents ---
    for (int k = cnt - 1; k >= 0; --k) {
      int p = sO[b][k];
      int l = sL[b][p], r = sR[b][p];
      if (l >= 0 || r >= 0) {
        int hl = (l >= 0) ? (int)sLev[b][l] : 0;
        int hr = (r >= 0) ? (int)sLev[b][r] : 0;
        sLev[b][p] = (unsigned char)(1 + (hl > hr ? hl : hr));
      }
    }
    atomicMax(&sMaxLev, (int)sLev[b][root]);
    for (int p = 0; p < len; ++p)
      if (sLev[b][p]) atomicAdd(&sHist[sLev[b][p]], 1);
  }
  __syncthreads();
  if (tid == 0) {
    int off2 = 0;
    for (int r = 1; r <= 128; ++r) {
      meta[MO_LSTART + r] = off2;
      sCur[r] = off2;
      meta[MO_LCOUNT + r] = sHist[r];
      off2 += sHist[r];
    }
    meta[MO_MAXLEV] = sMaxLev;
  }
  __syncthreads();
  if (tid < B_) {
    const int b = tid;
    int len = lens[b];
    if (len < 2) len = 2;
    if (len > 128) len = 128;
    for (int p = 0; p < len; ++p) if (sLev[b][p]) {
      int l = sL[b][p], r = sR[b][p];
      // encode: empty -> 128, Cartesian leaf -> raw index, compose -> 129+idx
      int le = (l < 0) ? 128 : (sLev[b][l] ? 129 + l : l);
      int re = (r < 0) ? 128 : (sLev[b][r] ? 129 + r : r);
      int idx = atomicAdd(&sCur[sLev[b][p]], 1);
      meta[MO_NODES + idx] = (b << 25) | (p << 18) | (le << 9) | re;
    }
  }
}

// ---------------- K_forest: ALL tree levels in one persistent dispatch -------
// FGRID=512 blocks = FGRP=8 tile groups x 64 col-slices, 384 threads.
// __launch_bounds__(384,4) caps VGPR at 128 -> 4 waves/SIMD -> 2 blocks/CU ->
// all 512 blocks CO-RESIDENT (required: level barrier would deadlock if not).
// Inner dot-product restructured: explicit seg loop (compile-time pointer
// select, no runtime-indexed pointer array) + unroll 4 (20 loads in flight,
// one latency stall per 4 k-steps instead of per step).
__global__ __launch_bounds__(384, 4) void k_forest(const u16* __restrict__ Wc,
    const float* __restrict__ bcomp, const u16* __restrict__ nodeH,
    const float* __restrict__ nodeC, u16* __restrict__ compH,
    float* __restrict__ compC, int* meta)
{
  const int hs = blockIdx.x & 63, mb4 = blockIdx.x >> 6;   // mb4 in [0,FGRP)
  const int tid = threadIdx.x;
  const int w = tid >> 6, lane = tid & 63;
  const int l15 = lane & 15, quad = lane >> 4;
  __shared__ float sG[6][64][17];
  __shared__ int sInfo[64];
  int* cnt = meta + MO_CNT;
  const int maxLev = meta[MO_MAXLEV];
  const size_t brow = (size_t)(w * 1024 + hs * 16 + l15) * K3_;
  const int koq = quad * 8;

  for (int rd = 1; rd <= maxLev && rd <= 128; ++rd) {
    const int M = meta[MO_LCOUNT + rd];
    const int base = meta[MO_LSTART + rd];
    int ntiles = (M + 63) >> 6;
    if (ntiles > 32) ntiles = 32;
    for (int tile = mb4; tile < ntiles; tile += FGRP) {
      if (tid < 64) {
        int j = tile * 64 + tid; if (j >= M) j = M - 1;
        sInfo[tid] = meta[MO_NODES + base + j];
      }
      __syncthreads();
      {
        const u16* aseg[3][4];
#pragma unroll
        for (int mi = 0; mi < 4; ++mi) {
          int info = sInfo[mi * 16 + l15];
          int b = (info >> 25) & 31, p = (info >> 18) & 127;
          int li = (info >> 9) & 0x1FF, ri = info & 0x1FF;
          aseg[0][mi] = (li <= 128) ? nodeH + ((size_t)(b * 129 + li) << 10)
                                    : compH + ((size_t)(b * 128 + li - 129) << 10);
          aseg[1][mi] = nodeH + ((size_t)(b * 129 + p) << 10);
          aseg[2][mi] = (ri <= 128) ? nodeH + ((size_t)(b * 129 + ri) << 10)
                                    : compH + ((size_t)(b * 128 + ri - 129) << 10);
        }
        floatx4 acc[4] = {};
#pragma unroll
        for (int seg = 0; seg < 3; ++seg) {
          const u16* A0 = aseg[seg][0] + koq;
          const u16* A1 = aseg[seg][1] + koq;
          const u16* A2 = aseg[seg][2] + koq;
          const u16* A3 = aseg[seg][3] + koq;
          const u16* Bp = Wc + brow + (size_t)seg * 1024 + koq;
#pragma unroll 4
          for (int k2 = 0; k2 < 32; ++k2) {
            int ko = k2 * 32;
            short8 bfr = *(const short8*)(Bp + ko);
            acc[0] = MFMA(*(const short8*)(A0 + ko), bfr, acc[0]);
            acc[1] = MFMA(*(const short8*)(A1 + ko), bfr, acc[1]);
            acc[2] = MFMA(*(const short8*)(A2 + ko), bfr, acc[2]);
            acc[3] = MFMA(*(const short8*)(A3 + ko), bfr, acc[3]);
          }
        }
#pragma unroll
        for (int mi = 0; mi < 4; ++mi)
#pragma unroll
          for (int r = 0; r < 4; ++r) sG[w][mi * 16 + quad * 4 + r][l15] = acc[mi][r];
      }
      __syncthreads();
      for (int idx = tid; idx < 1024; idx += 384) {
        int j_loc = idx >> 4, col = idx & 15;
        int j = tile * 64 + j_loc;
        if (j < M) {
          int info = sInfo[j_loc];
          int b = (info >> 25) & 31, p = (info >> 18) & 127;
          int li = (info >> 9) & 0x1FF, ri = info & 0x1FF;
          int hc = hs * 16 + col;
          float gi  = sG[0][j_loc][col] + bcomp[hc];
          float gfl = sG[1][j_loc][col] + bcomp[H_ + hc];
          float gfx = sG[2][j_loc][col] + bcomp[2 * H_ + hc];
          float gfr = sG[3][j_loc][col] + bcomp[3 * H_ + hc];
          float gu  = sG[4][j_loc][col] + bcomp[4 * H_ + hc];
          float go  = sG[5][j_loc][col] + bcomp[5 * H_ + hc];
          float cl  = (li <= 128) ? nodeC[(size_t)(b * 129 + li) * H_ + hc]
                                  : compC[(size_t)(b * 128 + li - 129) * H_ + hc];
          float cx  = nodeC[(size_t)(b * 129 + p) * H_ + hc];
          float cr2 = (ri <= 128) ? nodeC[(size_t)(b * 129 + ri) * H_ + hc]
                                  : compC[(size_t)(b * 128 + ri - 129) * H_ + hc];
          float c = sigf(gi) * tanh_(gu) + sigf(gfl) * cl + sigf(gfx) * cx + sigf(gfr) * cr2;
          float h = sigf(go) * tanh_(c);
          __hip_atomic_store(&compH[(size_t)(b * 128 + p) * H_ + hc], f2b(h),
                             __ATOMIC_RELAXED, __HIP_MEMORY_SCOPE_AGENT);
          __hip_atomic_store(&compC[(size_t)(b * 128 + p) * H_ + hc], c,
                             __ATOMIC_RELAXED, __HIP_MEMORY_SCOPE_AGENT);
        }
      }
      __syncthreads();
    }
    // ---- level barrier: drain stores, arrive, spin until all FGRID arrived --
    __syncthreads();               // compiler drains vmcnt before s_barrier
    if (tid == 0) atomicAdd(&cnt[rd], 1);
    if (tid < 64) {
      int it = 0;
      for (;;) {
        int v = __hip_atomic_load(&cnt[rd], __ATOMIC_RELAXED, __HIP_MEMORY_SCOPE_AGENT);
        if (v >= FGRID || ++it >= SPIN_CAP2) break;
        __builtin_amdgcn_s_sleep(1);
      }
    }
    __syncthreads();
  }
}

// ---------------- K_round: fallback path (f32 weights, per-level dispatch) ---
template<int BF16B>
__global__ __launch_bounds__(384) void k_round(const void* __restrict__ Wc,
    const float* __restrict__ bcomp, const u16* __restrict__ nodeH,
    const float* __restrict__ nodeC, u16* __restrict__ compH,
    float* __restrict__ compC, const int* __restrict__ meta, int rd)
{
  const int M = meta[MO_LCOUNT + rd];
  if (M <= 0 || M > 2048) return;
  const int mb = blockIdx.x >> 6, hs = blockIdx.x & 63;
  if (mb * 64 >= M) return;
  const int base = meta[MO_LSTART + rd];
  const int tid = threadIdx.x;
  const int w = tid >> 6, lane = tid & 63;
  const int l15 = lane & 15, quad = lane >> 4;
  __shared__ float sG[6][64][17];
  __shared__ int sInfo[64];
  if (tid < 64) {
    int j = mb * 64 + tid; if (j >= M) j = M - 1;
    sInfo[tid] = meta[MO_NODES + base + j];
  }
  __syncthreads();
  {
    const u16* aseg[3][4];
#pragma unroll
    for (int mi = 0; mi < 4; ++mi) {
      int info = sInfo[mi * 16 + l15];
      int b = (info >> 25) & 31, p = (info >> 18) & 127;
      int li = (info >> 9) & 0x1FF, ri = info & 0x1FF;
      aseg[0][mi] = (li <= 128) ? nodeH + ((size_t)(b * 129 + li) << 10)
                                : compH + ((size_t)(b * 128 + li - 129) << 10);
      aseg[1][mi] = nodeH + ((size_t)(b * 129 + p) << 10);
      aseg[2][mi] = (ri <= 128) ? nodeH + ((size_t)(b * 129 + ri) << 10)
                                : compH + ((size_t)(b * 128 + ri - 129) << 10);
    }
    floatx4 acc[4] = {};
    const size_t brow = (size_t)(w * 1024 + hs * 16 + l15) * K3_;
    for (int kc = 0; kc < 96; ++kc) {
      int seg = kc >> 5, ko = (kc & 31) * 32 + quad * 8;
      short8 bfr;
      if (BF16B) bfr = *(const short8*)((const u16*)Wc + brow + kc * 32 + quad * 8);
      else       bfr = cvt8((const float*)Wc + brow + kc * 32 + quad * 8);
      acc[0] = MFMA(*(const short8*)(aseg[seg][0] + ko), bfr, acc[0]);
      acc[1] = MFMA(*(const short8*)(aseg[seg][1] + ko), bfr, acc[1]);
      acc[2] = MFMA(*(const short8*)(aseg[seg][2] + ko), bfr, acc[2]);
      acc[3] = MFMA(*(const short8*)(aseg[seg][3] + ko), bfr, acc[3]);
    }
#pragma unroll
    for (int mi = 0; mi < 4; ++mi)
#pragma unroll
      for (int r = 0; r < 4; ++r) sG[w][mi * 16 + quad * 4 + r][l15] = acc[mi][r];
  }
  __syncthreads();
  for (int idx = tid; idx < 1024; idx += 384) {
    int j_loc = idx >> 4, col = idx & 15;
    int j = mb * 64 + j_loc;
    if (j < M) {
      int info = sInfo[j_loc];
      int b = (info >> 25) & 31, p = (info >> 18) & 127;
      int li = (info >> 9) & 0x1FF, ri = info & 0x1FF;
      int hc = hs * 16 + col;
      float gi  = sG[0][j_loc][col] + bcomp[hc];
      float gfl = sG[1][j_loc][col] + bcomp[H_ + hc];
      float gfx = sG[2][j_loc][col] + bcomp[2 * H_ + hc];
      float gfr = sG[3][j_loc][col] + bcomp[3 * H_ + hc];
      float gu  = sG[4][j_loc][col] + bcomp[4 * H_ + hc];
      float go  = sG[5][j_loc][col] + bcomp[5 * H_ + hc];
      float cl  = (li <= 128) ? nodeC[(size_t)(b * 129 + li) * H_ + hc]
                              : compC[(size_t)(b * 128 + li - 129) * H_ + hc];
      float cx  = nodeC[(size_t)(b * 129 + p) * H_ + hc];
      float cr2 = (ri <= 128) ? nodeC[(size_t)(b * 129 + ri) * H_ + hc]
                              : compC[(size_t)(b * 128 + ri - 129) * H_ + hc];
      float c = sigf(gi) * tanh_(gu) + sigf(gfl) * cl + sigf(gfx) * cx + sigf(gfr) * cr2;
      float h = sigf(go) * tanh_(c);
      compH[(size_t)(b * 128 + p) * H_ + hc] = f2b(h);
      compC[(size_t)(b * 128 + p) * H_ + hc] = c;
    }
  }
}

// ---------------- K_out: emit root h then root c (f32) -----------------------
__global__ void k_out(const u16* __restrict__ compH, const float* __restrict__ compC,
                      const int* __restrict__ meta, float* __restrict__ out)
{
  int i = blockIdx.x * 256 + threadIdx.x;
  if (i >= 2 * B_ * H_) return;
  int part = i >> 15;
  int b = (i >> 10) & 31;
  int c = i & 1023;
  int root = meta[MO_ROOT + b] & 127;
  size_t rw = (size_t)(b * 128 + root) * H_ + c;
  out[i] = part ? compC[rw] : b2f(compH[rw]);
}

extern "C" void kernel_launch(void* const* d_in, const int* in_sizes, int n_in,
                              void* d_out, int out_size, void* d_ws, size_t ws_size,
                              hipStream_t stream)
{
  (void)in_sizes; (void)n_in; (void)out_size;
  const float* emb   = (const float*)d_in[0];
  const float* Wih   = (const float*)d_in[1];
  const float* Whh   = (const float*)d_in[2];
  const float* bih   = (const float*)d_in[3];
  const float* bhh   = (const float*)d_in[4];
  const float* Wcomp = (const float*)d_in[5];
  const float* bcomp = (const float*)d_in[6];
  const int* words   = (const int*)d_in[7];
  const int* lens    = (const int*)d_in[8];

  char* ws = (char*)d_ws;
  size_t off = 0;
  auto take = [&](size_t bytes) -> void* {
    void* p = ws + off; off += (bytes + 255) & ~(size_t)255; return p;
  };
  int*   meta  = (int*)  take((size_t)(512 + 4096 + 160) * 4);  // control first
  u16*   nodeH = (u16*)  take((size_t)B_ * 129 * H_ * 2);     // leaves + zero row
  float* nodeC = (float*)take((size_t)B_ * 129 * H_ * 4);
  u16*   embP  = (u16*)  take((size_t)B_ * L_ * DP_ * 2);
  u16*   WihP  = (u16*)  take((size_t)G4_ * DP_ * 2);
  u16*   hEx   = (u16*)  take((size_t)2 * B_ * H_ * 2);       // coherent h dbuf
  char*  xgreg = (char*) take((size_t)B_ * L_ * G4_ * 2);     // 33.5 MB
  u16*   Xg    = (u16*)  xgreg;
  u16*   compH = (u16*)  xgreg;                               // alias: dead Xg
  float* compC = (float*)(xgreg + (size_t)B_ * 128 * H_ * 2);
  // optional pre-converted bf16 Wcomp (37.75 MB) - only if ws has room
  u16* WcompB = nullptr;
  if (off + (size_t)6 * H_ * K3_ * 2 <= ws_size)
    WcompB = (u16*)take((size_t)6 * H_ * K3_ * 2);

  hipFuncSetAttribute((const void*)k_scan,
                      hipFuncAttributeMaxDynamicSharedMemorySize, SCAN_LDS);

  k_init<<<dim3(2048), dim3(256), 0, stream>>>(emb, Wih, Wcomp, embP, WihP,
                                               WcompB, nodeH, nodeC, meta);
  k_xg  <<<dim3(2048), dim3(256), 0, stream>>>(embP, WihP, bih, bhh, Xg);
  k_scan<<<dim3(64), dim3(256), SCAN_LDS, stream>>>(Whh, Xg, nodeH, nodeC, hEx, meta);
  k_tree<<<dim3(1), dim3(256), 0, stream>>>(words, lens, meta);
  if (WcompB) {
    k_forest<<<dim3(FGRID), dim3(384), 0, stream>>>(WcompB, bcomp, nodeH, nodeC,
                                                    compH, compC, meta);
  } else {
    for (int rd = 1; rd <= NROUNDS; ++rd) {
      int maxM = 32 * 128 / (rd + 1);
      if (maxM > 2048) maxM = 2048;
      int nb = ((maxM + 63) / 64) * 64;
      k_round<0><<<dim3(nb), dim3(384), 0, stream>>>(Wcomp, bcomp, nodeH, nodeC,
                                                     compH, compC, meta, rd);
    }
  }
  k_out<<<dim3(256), dim3(256), 0, stream>>>(compH, compC, meta, (float*)d_out);
}

// Round 5
// 2195.695 us; speedup vs baseline: 1.2798x; 1.2798x over previous
//
#include <hip/hip_runtime.h>

typedef unsigned short u16;
typedef __attribute__((ext_vector_type(8))) short short8;
typedef __attribute__((ext_vector_type(4))) float floatx4;

#define B_   32
#define L_   128
#define D_   300
#define DP_  320
#define H_   1024
#define G4_  4096
#define K3_  3072
#define NROUNDS 40        // fallback path only (f32 weights)

#define MO_MAXLEV 0
#define MO_ROOT   8
#define MO_LSTART 64
#define MO_LCOUNT 256
#define MO_FLG    448     // 64 scan barrier flags
#define MO_NODES  512
#define MO_CNT    4608    // 160 per-level arrival counters (k_forest)
#define SPIN_CAP  500000
#define SPIN_CAP2 200000

#define FGRID 512         // k_forest blocks: one per 2 h-cols; ALL co-resident

#define MFMA(a,b,c) __builtin_amdgcn_mfma_f32_16x16x32_bf16((a),(b),(c),0,0,0)

__device__ inline float b2f(u16 u){ union { unsigned int i; float f; } v; v.i = ((unsigned int)u) << 16; return v.f; }
__device__ inline u16 f2b(float f){ union { float f; unsigned int i; } v; v.f = f; unsigned int r = v.i + 0x7FFFu + ((v.i >> 16) & 1u); return (u16)(r >> 16); }
__device__ inline float h2f(u16 u){ union { _Float16 h; u16 s; } v; v.s = u; return (float)v.h; }
__device__ inline u16 f2h(float f){ union { _Float16 h; u16 s; } v; v.h = (_Float16)f; return v.s; }
__device__ inline float sigf(float x){ return 1.f / (1.f + __expf(-x)); }
__device__ inline float tanh_(float x){ return 1.f - 2.f / (__expf(2.f * x) + 1.f); }
__device__ inline short8 cvt8(const float* p){
  floatx4 a = *(const floatx4*)p, b = *(const floatx4*)(p + 4);
  short8 r;
  r[0]=(short)f2b(a[0]); r[1]=(short)f2b(a[1]); r[2]=(short)f2b(a[2]); r[3]=(short)f2b(a[3]);
  r[4]=(short)f2b(b[0]); r[5]=(short)f2b(b[1]); r[6]=(short)f2b(b[2]); r[7]=(short)f2b(b[3]);
  return r;
}

// ---------------- K_init: pad+convert inputs, zero state, optional Wcomp cvt -
__global__ void k_init(const float* __restrict__ emb, const float* __restrict__ Wih,
                       const float* __restrict__ Wcomp,
                       u16* __restrict__ embP, u16* __restrict__ WihP,
                       u16* __restrict__ WcompB,            // may be null
                       u16* __restrict__ nodeH, float* __restrict__ nodeC, int* meta)
{
  const int gtid = blockIdx.x * 256 + threadIdx.x;
  const int nT = 2048 * 256;
  if (gtid < 64) meta[MO_FLG + gtid] = 0;               // scan barrier flags
  for (int i = gtid; i < B_ * H_; i += nT) {            // zero row (leaf idx 128)
    int b = i >> 10, c = i & (H_ - 1);
    nodeH[(size_t)(b * 129 + 128) * H_ + c] = 0;
    nodeC[(size_t)(b * 129 + 128) * H_ + c] = 0.f;
  }
  for (int i = gtid; i < B_ * L_ * DP_; i += nT) {      // pad K 300 -> 320
    int r = i / DP_, k = i - r * DP_;
    embP[i] = (k < D_) ? f2b(emb[(size_t)r * D_ + k]) : (u16)0;
  }
  for (int i = gtid; i < G4_ * DP_; i += nT) {
    int r = i / DP_, k = i - r * DP_;
    WihP[i] = (k < D_) ? f2b(Wih[(size_t)r * D_ + k]) : (u16)0;
  }
  if (WcompB) {                                         // 6144x3072 f32 -> bf16
    for (int c = gtid; c < (6 * H_ * K3_) / 8; c += nT)
      *(short8*)(WcompB + (size_t)c * 8) = cvt8(Wcomp + (size_t)c * 8);
  }
}

// ---------------- K_xg: Xg[b*128+t][4096] = emb @ Wih^T + b_ih + b_hh (fp16) -
__global__ __launch_bounds__(256) void k_xg(const u16* __restrict__ embP,
    const u16* __restrict__ WihP, const float* __restrict__ bih,
    const float* __restrict__ bhh, u16* __restrict__ Xg)
{
  const int lane = threadIdx.x & 63, wave = threadIdx.x >> 6;
  const int l15 = lane & 15, quad = lane >> 4;
  const int gw = blockIdx.x * 4 + wave;
  for (int st = gw; st < 128 * 128; st += 2048 * 4) {
    int tm = st >> 7, tn = st & 127;
    int m0 = tm * 32, n0 = tn * 32;
    floatx4 acc[2][2] = {};
    for (int kc = 0; kc < DP_ / 32; ++kc) {
      int ko = kc * 32 + quad * 8;
      short8 a0 = *(const short8*)(embP + (size_t)(m0 + l15) * DP_ + ko);
      short8 a1 = *(const short8*)(embP + (size_t)(m0 + 16 + l15) * DP_ + ko);
      short8 b0 = *(const short8*)(WihP + (size_t)(n0 + l15) * DP_ + ko);
      short8 b1 = *(const short8*)(WihP + (size_t)(n0 + 16 + l15) * DP_ + ko);
      acc[0][0] = MFMA(a0, b0, acc[0][0]);
      acc[0][1] = MFMA(a0, b1, acc[0][1]);
      acc[1][0] = MFMA(a1, b0, acc[1][0]);
      acc[1][1] = MFMA(a1, b1, acc[1][1]);
    }
    for (int mi = 0; mi < 2; ++mi)
      for (int ni = 0; ni < 2; ++ni)
        for (int r = 0; r < 4; ++r) {
          int m = m0 + mi * 16 + quad * 4 + r;
          int n = n0 + ni * 16 + l15;
          float v = acc[mi][ni][r] + bih[n] + bhh[n];
          Xg[(size_t)m * G4_ + n] = f2h(v);
        }
  }
}

// ---------------- K_scan: fence-free; B slice in TRUE VGPRs (full unroll) ----
#define SCAN_LDS (65536 + 4*32*17*4)
__global__ __launch_bounds__(256, 1) void k_scan(const float* __restrict__ Whh,
    const u16* __restrict__ Xg, u16* __restrict__ nodeH,
    float* __restrict__ nodeC, u16* __restrict__ hEx, int* meta)
{
  extern __shared__ char smem[];
  u16*   hst = (u16*)smem;                    // [32][1024] bf16, XOR-swizzled
  float* sG  = (float*)(smem + 65536);        // [4][32][17] gate pre-acts
  const int tid = threadIdx.x;
  const int g = tid >> 6, lane = tid & 63;
  const int l15 = lane & 15, quad = lane >> 4;
  const int n16 = blockIdx.x;
  int* flags = meta + MO_FLG;

  // B (gate g, cols n16*16..+16, all k) -> 128 persistent VGPRs (f32 -> bf16)
  short8 bf[32];
#pragma unroll
  for (int kc = 0; kc < 32; ++kc)
    bf[kc] = cvt8(Whh + ((size_t)(g * 1024 + n16 * 16 + l15)) * 1024 + kc * 32 + quad * 8);

  const int cb = g * 8 + (lane & 7);          // cell batch
  const int cp = lane >> 3;                   // cell col-pair
  const int c0 = n16 * 16 + cp * 2;

  float cst0 = 0.f, cst1 = 0.f;
  for (int t = 0; t < L_; ++t) {
    // prefetch this step's Xg gate inputs (independent of h(t-1))
    float xv[4][2];
    {
      const u16* xr = Xg + (size_t)(cb * 128 + t) * G4_;
#pragma unroll
      for (int gg = 0; gg < 4; ++gg)
#pragma unroll
        for (int u = 0; u < 2; ++u)
          xv[gg][u] = h2f(xr[gg * 1024 + c0 + u]);
    }
    floatx4 acc[2] = {};
    if (t > 0) {
      // stage h(t-1): 8192 u64 agent-coherent loads -> swizzled LDS
      const unsigned long long* src =
          (const unsigned long long*)(hEx + ((t - 1) & 1) * (B_ * H_));
#pragma unroll
      for (int ch = 0; ch < 2; ++ch) {
        unsigned long long tmp[16];
#pragma unroll
        for (int q = 0; q < 16; ++q)
          tmp[q] = __hip_atomic_load(src + (ch * 16 + q) * 256 + tid,
                                     __ATOMIC_RELAXED, __HIP_MEMORY_SCOPE_AGENT);
#pragma unroll
        for (int q = 0; q < 16; ++q) {
          int idx = (ch * 16 + q) * 256 + tid;
          int b = idx >> 8, g8 = idx & 255, gr = g8 >> 1;
          *(unsigned long long*)(hst + (b << 10) + ((gr ^ (b & 7)) << 3) + (g8 & 1) * 4) = tmp[q];
        }
      }
      __syncthreads();
#pragma unroll
      for (int kc = 0; kc < 32; ++kc) {       // FULL unroll -> bf[] stays in VGPRs
        int gr = (kc * 4 + quad) ^ (l15 & 7);
        short8 a0 = *(const short8*)(hst + (l15 << 10) + (gr << 3));
        short8 a1 = *(const short8*)(hst + ((16 + l15) << 10) + (gr << 3));
        acc[0] = MFMA(a0, bf[kc], acc[0]);
        acc[1] = MFMA(a1, bf[kc], acc[1]);
      }
    }
#pragma unroll
    for (int mt = 0; mt < 2; ++mt)
#pragma unroll
      for (int r = 0; r < 4; ++r)
        sG[(g * 32 + mt * 16 + quad * 4 + r) * 17 + l15] = acc[mt][r];
    __syncthreads();
    // cell update
    {
      float cc[2] = { cst0, cst1 };
      float hh[2];
#pragma unroll
      for (int u = 0; u < 2; ++u) {
        int col = cp * 2 + u;
        float iv = sG[(0 * 32 + cb) * 17 + col] + xv[0][u];
        float fv = sG[(1 * 32 + cb) * 17 + col] + xv[1][u];
        float gv = sG[(2 * 32 + cb) * 17 + col] + xv[2][u];
        float ov = sG[(3 * 32 + cb) * 17 + col] + xv[3][u];
        float c = sigf(fv) * cc[u] + sigf(iv) * tanh_(gv);
        float h = sigf(ov) * tanh_(c);
        cc[u] = c; hh[u] = h;
      }
      cst0 = cc[0]; cst1 = cc[1];
      unsigned pack = (unsigned)f2b(hh[0]) | ((unsigned)f2b(hh[1]) << 16);
      __hip_atomic_store((unsigned*)(hEx + (t & 1) * (B_ * H_)) + (cb << 9) + (c0 >> 1),
                         pack, __ATOMIC_RELAXED, __HIP_MEMORY_SCOPE_AGENT);
      *(unsigned*)(nodeH + (size_t)(cb * 129 + t) * H_ + c0) = pack;   // leaf archive
      *(float2*)(nodeC + (size_t)(cb * 129 + t) * H_ + c0) = make_float2(cc[0], cc[1]);
    }
    __syncthreads();   // drains vmcnt for all waves before flag release
    if (tid == 0)
      __hip_atomic_store(&flags[n16], t + 1, __ATOMIC_RELAXED, __HIP_MEMORY_SCOPE_AGENT);
    if (g == 0) {      // wave 0: one flag per lane, ballot across 64 blocks
      int it = 0;
      for (;;) {
        int v = __hip_atomic_load(&flags[lane], __ATOMIC_RELAXED, __HIP_MEMORY_SCOPE_AGENT);
        if (__all(v >= t + 1) || ++it >= SPIN_CAP) break;
        __builtin_amdgcn_s_sleep(1);
      }
    }
    __syncthreads();
  }
}

// ---------------- K_tree: O(n) Cartesian trees + O(n) level schedule ---------
__global__ void k_tree(const int* __restrict__ words, const int* __restrict__ lens,
                       int* meta)
{
  const int tid = threadIdx.x;
  __shared__ u16 sD[B_][L_];
  __shared__ short sL[B_][L_], sR[B_][L_];     // raw child indices, -1 = none
  __shared__ short sS[B_][130];                // stack (build, then preorder)
  __shared__ short sO[B_][L_];                 // preorder sequence
  __shared__ unsigned char sLev[B_][L_];       // height; 0 = Cartesian leaf
  __shared__ int sHist[132], sCur[132], sMaxLev;
  for (int i = tid; i < 132; i += 256) { sHist[i] = 0; sCur[i] = 0; }
  if (tid == 0) sMaxLev = 1;
  for (int i = tid; i < 160; i += 256) meta[MO_CNT + i] = 0;   // forest counters
  for (int i = tid; i < B_ * L_; i += 256) {   // parallel, coalesced init
    int b = i >> 7, t = i & 127;
    sD[b][t] = (u16)(words[i] % 1000);
    sL[b][t] = -1; sR[b][t] = -1; sLev[b][t] = 0;
  }
  __syncthreads();
  if (tid < B_) {
    const int b = tid;
    int len = lens[b];
    if (len < 2) len = 2;
    if (len > 128) len = 128;
    // --- 1. monotone-stack Cartesian min-tree (ties: leftmost is ancestor) ---
    int sp = 0;
    for (int i = 0; i < len; ++i) {
      int v = sD[b][i];
      int last = -1;
      while (sp > 0) {
        int top = sS[b][sp - 1];
        if ((int)sD[b][top] > v) { last = top; --sp; } else break;
      }
      sL[b][i] = (short)last;                  // last popped = left child of i
      if (sp > 0) sR[b][sS[b][sp - 1]] = (short)i; // i = (current) right child
      sS[b][sp++] = (short)i;
    }
    const int root = sS[b][0];                 // stack bottom = global min
    meta[MO_ROOT + b] = root;
    // --- 2a. preorder via explicit stack ---
    int cnt = 0, tp = 0;
    sS[b][tp++] = (short)root;
    while (tp > 0) {
      int p = sS[b][--tp];
      sO[b][cnt++] = (short)p;
      int l = sL[b][p], r = sR[b][p];
      if (l >= 0) sS[b][tp++] = (short)l;
      if (r >= 0) sS[b][tp++] = (short)r;
    }
    // --- 2b. reverse preorder: children processed before parents ---
    for (int k = cnt - 1; k >= 0; --k) {
      int p = sO[b][k];
      int l = sL[b][p], r = sR[b][p];
      if (l >= 0 || r >= 0) {
        int hl = (l >= 0) ? (int)sLev[b][l] : 0;
        int hr = (r >= 0) ? (int)sLev[b][r] : 0;
        sLev[b][p] = (unsigned char)(1 + (hl > hr ? hl : hr));
      }
    }
    atomicMax(&sMaxLev, (int)sLev[b][root]);
    for (int p = 0; p < len; ++p)
      if (sLev[b][p]) atomicAdd(&sHist[sLev[b][p]], 1);
  }
  __syncthreads();
  if (tid == 0) {
    int off2 = 0;
    for (int r = 1; r <= 128; ++r) {
      meta[MO_LSTART + r] = off2;
      sCur[r] = off2;
      meta[MO_LCOUNT + r] = sHist[r];
      off2 += sHist[r];
    }
    meta[MO_MAXLEV] = sMaxLev;
  }
  __syncthreads();
  if (tid < B_) {
    const int b = tid;
    int len = lens[b];
    if (len < 2) len = 2;
    if (len > 128) len = 128;
    for (int p = 0; p < len; ++p) if (sLev[b][p]) {
      int l = sL[b][p], r = sR[b][p];
      // encode: empty -> 128, Cartesian leaf -> raw index, compose -> 129+idx
      int le = (l < 0) ? 128 : (sLev[b][l] ? 129 + l : l);
      int re = (r < 0) ? 128 : (sLev[b][r] ? 129 + r : r);
      int idx = atomicAdd(&sCur[sLev[b][p]], 1);
      meta[MO_NODES + idx] = (b << 25) | (p << 18) | (le << 9) | re;
    }
  }
}

// ---------------- K_forest: weight-stationary-in-LDS persistent kernel ------
// 512 blocks x 256 thr. Block bcol owns h-cols {2*bcol, 2*bcol+1}: its 12
// weight rows (6 gates x 2 cols) x K3072 bf16 = 72KB live in LDS for the whole
// kernel, loaded ONCE (37.75MB HBM total, exactly once -- kills the 405MB/level
// re-stream that was the 50-60us/level floor). Every block processes every
// node tile (4 waves x 16 nodes, 1 MFMA n-frag with rows 12-15 clamped).
// All 6 gates of a (node,col) are block-local -> nonlinearity local; compC is
// block-private (plain stores); compH cross-block via agent stores (proven).
// LDS layout wlds[384 slots][12 rows][16B]: slot=(kc*4+quad); staging writes
// are LDS-linear (addr = j*16); frag reads 2-way conflict (free).
// Co-residency: 77KB LDS -> 2 blocks/CU, 512 total (proven in round 4).
#define FOREST_LDS (73728 + 3072 + 256)
__global__ __launch_bounds__(256) void k_forest(const u16* __restrict__ Wc,
    const float* __restrict__ bcomp, const u16* __restrict__ nodeH,
    const float* __restrict__ nodeC, u16* __restrict__ compH,
    float* __restrict__ compC, int* meta)
{
  extern __shared__ char smem[];
  u16*   wlds  = (u16*)smem;                     // [384][12][8] bf16
  float* sG    = (float*)(smem + 73728);         // [4][12][16]
  int*   sInfo = (int*)(smem + 73728 + 3072);    // [64]
  const int bcol = blockIdx.x;                   // owns cols 2*bcol, 2*bcol+1
  const int tid = threadIdx.x;
  const int w = tid >> 6, lane = tid & 63;
  const int l15 = lane & 15, quad = lane >> 4;
  int* cnt = meta + MO_CNT;
  const int maxLev = meta[MO_MAXLEV];

  // ---- stage my 12 weight rows into LDS (once). j = idx*12 + r12 -> LDS
  //      address j*16 is linear in tid (conflict-free ds_write_b128).
  for (int j = tid; j < 4608; j += 256) {
    int r12 = j % 12, idx = j / 12;              // idx = kc*4+quad chunk
    int G = (r12 >> 1) * 1024 + bcol * 2 + (r12 & 1);
    *(short8*)(wlds + (size_t)j * 8) = *(const short8*)(Wc + (size_t)G * K3_ + idx * 8);
  }
  __syncthreads();

  const int rclamp = (l15 < 12) ? l15 : 0;       // frag rows 12-15: dummy

  for (int rd = 1; rd <= maxLev && rd <= 128; ++rd) {
    const int M = meta[MO_LCOUNT + rd];
    const int base = meta[MO_LSTART + rd];
    const int ntiles = (M + 63) >> 6;
    for (int tile = 0; tile < ntiles; ++tile) {
      __syncthreads();                           // sInfo/sG reuse guard
      if (tid < 64) {
        int j = tile * 64 + tid; if (j >= M) j = M - 1;
        sInfo[tid] = meta[MO_NODES + base + j];
      }
      __syncthreads();
      // --- MFMA: wave w = m-tile (nodes tile*64+w*16 .. +16), lane l15 = node
      {
        int info = sInfo[w * 16 + l15];
        int b = (info >> 25) & 31, p = (info >> 18) & 127;
        int li = (info >> 9) & 0x1FF, ri = info & 0x1FF;
        const u16* A0 = (li <= 128) ? nodeH + ((size_t)(b * 129 + li) << 10)
                                    : compH + ((size_t)(b * 128 + li - 129) << 10);
        const u16* A1 = nodeH + ((size_t)(b * 129 + p) << 10);
        const u16* A2 = (ri <= 128) ? nodeH + ((size_t)(b * 129 + ri) << 10)
                                    : compH + ((size_t)(b * 128 + ri - 129) << 10);
        const u16* Aseg[3] = { A0, A1, A2 };
        floatx4 acc = {};
#pragma unroll
        for (int seg = 0; seg < 3; ++seg) {
          const u16* Ap = Aseg[seg] + quad * 8;
          const u16* Bp = wlds + ((size_t)((seg * 128 + quad) * 12 + rclamp)) * 8;
#pragma unroll 4
          for (int kcL = 0; kcL < 32; ++kcL) {
            short8 av = *(const short8*)(Ap + kcL * 32);
            short8 bv = *(const short8*)(Bp + kcL * 384);
            acc = MFMA(av, bv, acc);
          }
        }
        if (l15 < 12) {
#pragma unroll
          for (int r = 0; r < 4; ++r)
            sG[w * 192 + l15 * 16 + quad * 4 + r] = acc[r];
        }
      }
      __syncthreads();
      // --- epilogue: 128 threads = 64 nodes x 2 cols (block-local gates) ----
      if (tid < 128) {
        int j_loc = tid >> 1, c = tid & 1;
        int j = tile * 64 + j_loc;
        if (j < M) {
          int info = sInfo[j_loc];
          int b = (info >> 25) & 31, p = (info >> 18) & 127;
          int li = (info >> 9) & 0x1FF, ri = info & 0x1FF;
          int hc = bcol * 2 + c;
          const float* gq = sG + (j_loc >> 4) * 192 + c * 16 + (j_loc & 15);
          float gi  = gq[0 * 32] + bcomp[hc];
          float gfl = gq[1 * 32] + bcomp[H_ + hc];
          float gfx = gq[2 * 32] + bcomp[2 * H_ + hc];
          float gfr = gq[3 * 32] + bcomp[3 * H_ + hc];
          float gu  = gq[4 * 32] + bcomp[4 * H_ + hc];
          float go  = gq[5 * 32] + bcomp[5 * H_ + hc];
          float cl  = (li <= 128) ? nodeC[(size_t)(b * 129 + li) * H_ + hc]
                                  : compC[(size_t)(b * 128 + li - 129) * H_ + hc];
          float cx  = nodeC[(size_t)(b * 129 + p) * H_ + hc];
          float cr2 = (ri <= 128) ? nodeC[(size_t)(b * 129 + ri) * H_ + hc]
                                  : compC[(size_t)(b * 128 + ri - 129) * H_ + hc];
          float cc = sigf(gi) * tanh_(gu) + sigf(gfl) * cl + sigf(gfx) * cx + sigf(gfr) * cr2;
          float hh = sigf(go) * tanh_(cc);
          __hip_atomic_store(&compH[(size_t)(b * 128 + p) * H_ + hc], f2b(hh),
                             __ATOMIC_RELAXED, __HIP_MEMORY_SCOPE_AGENT);
          compC[(size_t)(b * 128 + p) * H_ + hc] = cc;   // block-private cols
        }
      }
    }
    // ---- level barrier: __syncthreads drains stores; arrive; 1-lane spin ----
    __syncthreads();
    if (tid == 0) {
      atomicAdd(&cnt[rd], 1);
      int it = 0;
      while (__hip_atomic_load(&cnt[rd], __ATOMIC_RELAXED, __HIP_MEMORY_SCOPE_AGENT)
                 < FGRID && ++it < SPIN_CAP2)
        __builtin_amdgcn_s_sleep(2);
    }
    __syncthreads();
  }
}

// ---------------- K_round: fallback path (f32 weights, per-level dispatch) ---
template<int BF16B>
__global__ __launch_bounds__(384) void k_round(const void* __restrict__ Wc,
    const float* __restrict__ bcomp, const u16* __restrict__ nodeH,
    const float* __restrict__ nodeC, u16* __restrict__ compH,
    float* __restrict__ compC, const int* __restrict__ meta, int rd)
{
  const int M = meta[MO_LCOUNT + rd];
  if (M <= 0 || M > 2048) return;
  const int mb = blockIdx.x >> 6, hs = blockIdx.x & 63;
  if (mb * 64 >= M) return;
  const int base = meta[MO_LSTART + rd];
  const int tid = threadIdx.x;
  const int w = tid >> 6, lane = tid & 63;
  const int l15 = lane & 15, quad = lane >> 4;
  __shared__ float sG[6][64][17];
  __shared__ int sInfo[64];
  if (tid < 64) {
    int j = mb * 64 + tid; if (j >= M) j = M - 1;
    sInfo[tid] = meta[MO_NODES + base + j];
  }
  __syncthreads();
  {
    const u16* aseg[3][4];
#pragma unroll
    for (int mi = 0; mi < 4; ++mi) {
      int info = sInfo[mi * 16 + l15];
      int b = (info >> 25) & 31, p = (info >> 18) & 127;
      int li = (info >> 9) & 0x1FF, ri = info & 0x1FF;
      aseg[0][mi] = (li <= 128) ? nodeH + ((size_t)(b * 129 + li) << 10)
                                : compH + ((size_t)(b * 128 + li - 129) << 10);
      aseg[1][mi] = nodeH + ((size_t)(b * 129 + p) << 10);
      aseg[2][mi] = (ri <= 128) ? nodeH + ((size_t)(b * 129 + ri) << 10)
                                : compH + ((size_t)(b * 128 + ri - 129) << 10);
    }
    floatx4 acc[4] = {};
    const size_t brow = (size_t)(w * 1024 + hs * 16 + l15) * K3_;
    for (int kc = 0; kc < 96; ++kc) {
      int seg = kc >> 5, ko = (kc & 31) * 32 + quad * 8;
      short8 bfr;
      if (BF16B) bfr = *(const short8*)((const u16*)Wc + brow + kc * 32 + quad * 8);
      else       bfr = cvt8((const float*)Wc + brow + kc * 32 + quad * 8);
      acc[0] = MFMA(*(const short8*)(aseg[seg][0] + ko), bfr, acc[0]);
      acc[1] = MFMA(*(const short8*)(aseg[seg][1] + ko), bfr, acc[1]);
      acc[2] = MFMA(*(const short8*)(aseg[seg][2] + ko), bfr, acc[2]);
      acc[3] = MFMA(*(const short8*)(aseg[seg][3] + ko), bfr, acc[3]);
    }
#pragma unroll
    for (int mi = 0; mi < 4; ++mi)
#pragma unroll
      for (int r = 0; r < 4; ++r) sG[w][mi * 16 + quad * 4 + r][l15] = acc[mi][r];
  }
  __syncthreads();
  for (int idx = tid; idx < 1024; idx += 384) {
    int j_loc = idx >> 4, col = idx & 15;
    int j = mb * 64 + j_loc;
    if (j < M) {
      int info = sInfo[j_loc];
      int b = (info >> 25) & 31, p = (info >> 18) & 127;
      int li = (info >> 9) & 0x1FF, ri = info & 0x1FF;
      int hc = hs * 16 + col;
      float gi  = sG[0][j_loc][col] + bcomp[hc];
      float gfl = sG[1][j_loc][col] + bcomp[H_ + hc];
      float gfx = sG[2][j_loc][col] + bcomp[2 * H_ + hc];
      float gfr = sG[3][j_loc][col] + bcomp[3 * H_ + hc];
      float gu  = sG[4][j_loc][col] + bcomp[4 * H_ + hc];
      float go  = sG[5][j_loc][col] + bcomp[5 * H_ + hc];
      float cl  = (li <= 128) ? nodeC[(size_t)(b * 129 + li) * H_ + hc]
                              : compC[(size_t)(b * 128 + li - 129) * H_ + hc];
      float cx  = nodeC[(size_t)(b * 129 + p) * H_ + hc];
      float cr2 = (ri <= 128) ? nodeC[(size_t)(b * 129 + ri) * H_ + hc]
                              : compC[(size_t)(b * 128 + ri - 129) * H_ + hc];
      float c = sigf(gi) * tanh_(gu) + sigf(gfl) * cl + sigf(gfx) * cx + sigf(gfr) * cr2;
      float h = sigf(go) * tanh_(c);
      compH[(size_t)(b * 128 + p) * H_ + hc] = f2b(h);
      compC[(size_t)(b * 128 + p) * H_ + hc] = c;
    }
  }
}

// ---------------- K_out: emit root h then root c (f32) -----------------------
__global__ void k_out(const u16* __restrict__ compH, const float* __restrict__ compC,
                      const int* __restrict__ meta, float* __restrict__ out)
{
  int i = blockIdx.x * 256 + threadIdx.x;
  if (i >= 2 * B_ * H_) return;
  int part = i >> 15;
  int b = (i >> 10) & 31;
  int c = i & 1023;
  int root = meta[MO_ROOT + b] & 127;
  size_t rw = (size_t)(b * 128 + root) * H_ + c;
  out[i] = part ? compC[rw] : b2f(compH[rw]);
}

extern "C" void kernel_launch(void* const* d_in, const int* in_sizes, int n_in,
                              void* d_out, int out_size, void* d_ws, size_t ws_size,
                              hipStream_t stream)
{
  (void)in_sizes; (void)n_in; (void)out_size;
  const float* emb   = (const float*)d_in[0];
  const float* Wih   = (const float*)d_in[1];
  const float* Whh   = (const float*)d_in[2];
  const float* bih   = (const float*)d_in[3];
  const float* bhh   = (const float*)d_in[4];
  const float* Wcomp = (const float*)d_in[5];
  const float* bcomp = (const float*)d_in[6];
  const int* words   = (const int*)d_in[7];
  const int* lens    = (const int*)d_in[8];

  char* ws = (char*)d_ws;
  size_t off = 0;
  auto take = [&](size_t bytes) -> void* {
    void* p = ws + off; off += (bytes + 255) & ~(size_t)255; return p;
  };
  int*   meta  = (int*)  take((size_t)(512 + 4096 + 160) * 4);  // control first
  u16*   nodeH = (u16*)  take((size_t)B_ * 129 * H_ * 2);     // leaves + zero row
  float* nodeC = (float*)take((size_t)B_ * 129 * H_ * 4);
  u16*   embP  = (u16*)  take((size_t)B_ * L_ * DP_ * 2);
  u16*   WihP  = (u16*)  take((size_t)G4_ * DP_ * 2);
  u16*   hEx   = (u16*)  take((size_t)2 * B_ * H_ * 2);       // coherent h dbuf
  char*  xgreg = (char*) take((size_t)B_ * L_ * G4_ * 2);     // 33.5 MB
  u16*   Xg    = (u16*)  xgreg;
  u16*   compH = (u16*)  xgreg;                               // alias: dead Xg
  float* compC = (float*)(xgreg + (size_t)B_ * 128 * H_ * 2);
  // optional pre-converted bf16 Wcomp (37.75 MB) - only if ws has room
  u16* WcompB = nullptr;
  if (off + (size_t)6 * H_ * K3_ * 2 <= ws_size)
    WcompB = (u16*)take((size_t)6 * H_ * K3_ * 2);

  hipFuncSetAttribute((const void*)k_scan,
                      hipFuncAttributeMaxDynamicSharedMemorySize, SCAN_LDS);
  hipFuncSetAttribute((const void*)k_forest,
                      hipFuncAttributeMaxDynamicSharedMemorySize, FOREST_LDS);

  k_init<<<dim3(2048), dim3(256), 0, stream>>>(emb, Wih, Wcomp, embP, WihP,
                                               WcompB, nodeH, nodeC, meta);
  k_xg  <<<dim3(2048), dim3(256), 0, stream>>>(embP, WihP, bih, bhh, Xg);
  k_scan<<<dim3(64), dim3(256), SCAN_LDS, stream>>>(Whh, Xg, nodeH, nodeC, hEx, meta);
  k_tree<<<dim3(1), dim3(256), 0, stream>>>(words, lens, meta);
  if (WcompB) {
    k_forest<<<dim3(FGRID), dim3(256), FOREST_LDS, stream>>>(WcompB, bcomp, nodeH,
                                                             nodeC, compH, compC, meta);
  } else {
    for (int rd = 1; rd <= NROUNDS; ++rd) {
      int maxM = 32 * 128 / (rd + 1);
      if (maxM > 2048) maxM = 2048;
      int nb = ((maxM + 63) / 64) * 64;
      k_round<0><<<dim3(nb), dim3(384), 0, stream>>>(Wcomp, bcomp, nodeH, nodeC,
                                                     compH, compC, meta, rd);
    }
  }
  k_out<<<dim3(256), dim3(256), 0, stream>>>(compH, compC, meta, (float*)d_out);
}

// Round 6
// 1816.460 us; speedup vs baseline: 1.5470x; 1.2088x over previous
//
#include <hip/hip_runtime.h>

typedef unsigned short u16;
typedef __attribute__((ext_vector_type(8))) short short8;
typedef __attribute__((ext_vector_type(4))) float floatx4;

#define B_   32
#define L_   128
#define D_   300
#define DP_  320
#define H_   1024
#define G4_  4096
#define K3_  3072
#define NROUNDS 40        // fallback path only (f32 weights)

#define MO_MAXLEV 0
#define MO_ROOT   8
#define MO_LSTART 64
#define MO_LCOUNT 256
#define MO_FLG    448     // 64 scan barrier flags
#define MO_NODES  512
#define MO_CNT    4608    // 256 per-block level-progress flags (k_forest)
#define SPIN_CAP  500000
#define SPIN_CAP2 200000

#define FGRID 256         // k_forest blocks: one per 4 h-cols; ALL co-resident
#define FTHREADS 512

#define MFMA(a,b,c) __builtin_amdgcn_mfma_f32_16x16x32_bf16((a),(b),(c),0,0,0)

__device__ inline float b2f(u16 u){ union { unsigned int i; float f; } v; v.i = ((unsigned int)u) << 16; return v.f; }
__device__ inline u16 f2b(float f){ union { float f; unsigned int i; } v; v.f = f; unsigned int r = v.i + 0x7FFFu + ((v.i >> 16) & 1u); return (u16)(r >> 16); }
__device__ inline float h2f(u16 u){ union { _Float16 h; u16 s; } v; v.s = u; return (float)v.h; }
__device__ inline u16 f2h(float f){ union { _Float16 h; u16 s; } v; v.h = (_Float16)f; return v.s; }
__device__ inline float sigf(float x){ return 1.f / (1.f + __expf(-x)); }
__device__ inline float tanh_(float x){ return 1.f - 2.f / (__expf(2.f * x) + 1.f); }
__device__ inline short8 cvt8(const float* p){
  floatx4 a = *(const floatx4*)p, b = *(const floatx4*)(p + 4);
  short8 r;
  r[0]=(short)f2b(a[0]); r[1]=(short)f2b(a[1]); r[2]=(short)f2b(a[2]); r[3]=(short)f2b(a[3]);
  r[4]=(short)f2b(b[0]); r[5]=(short)f2b(b[1]); r[6]=(short)f2b(b[2]); r[7]=(short)f2b(b[3]);
  return r;
}

// ---------------- K_init: pad+convert inputs, zero state, optional Wcomp cvt -
__global__ void k_init(const float* __restrict__ emb, const float* __restrict__ Wih,
                       const float* __restrict__ Wcomp,
                       u16* __restrict__ embP, u16* __restrict__ WihP,
                       u16* __restrict__ WcompB,            // may be null
                       u16* __restrict__ nodeH, float* __restrict__ nodeC, int* meta)
{
  const int gtid = blockIdx.x * 256 + threadIdx.x;
  const int nT = 2048 * 256;
  if (gtid < 64) meta[MO_FLG + gtid] = 0;               // scan barrier flags
  for (int i = gtid; i < B_ * H_; i += nT) {            // zero row (leaf idx 128)
    int b = i >> 10, c = i & (H_ - 1);
    nodeH[(size_t)(b * 129 + 128) * H_ + c] = 0;
    nodeC[(size_t)(b * 129 + 128) * H_ + c] = 0.f;
  }
  for (int i = gtid; i < B_ * L_ * DP_; i += nT) {      // pad K 300 -> 320
    int r = i / DP_, k = i - r * DP_;
    embP[i] = (k < D_) ? f2b(emb[(size_t)r * D_ + k]) : (u16)0;
  }
  for (int i = gtid; i < G4_ * DP_; i += nT) {
    int r = i / DP_, k = i - r * DP_;
    WihP[i] = (k < D_) ? f2b(Wih[(size_t)r * D_ + k]) : (u16)0;
  }
  if (WcompB) {                                         // 6144x3072 f32 -> bf16
    for (int c = gtid; c < (6 * H_ * K3_) / 8; c += nT)
      *(short8*)(WcompB + (size_t)c * 8) = cvt8(Wcomp + (size_t)c * 8);
  }
}

// ---------------- K_xg: Xg[b*128+t][4096] = emb @ Wih^T + b_ih + b_hh (fp16) -
__global__ __launch_bounds__(256) void k_xg(const u16* __restrict__ embP,
    const u16* __restrict__ WihP, const float* __restrict__ bih,
    const float* __restrict__ bhh, u16* __restrict__ Xg)
{
  const int lane = threadIdx.x & 63, wave = threadIdx.x >> 6;
  const int l15 = lane & 15, quad = lane >> 4;
  const int gw = blockIdx.x * 4 + wave;
  for (int st = gw; st < 128 * 128; st += 2048 * 4) {
    int tm = st >> 7, tn = st & 127;
    int m0 = tm * 32, n0 = tn * 32;
    floatx4 acc[2][2] = {};
    for (int kc = 0; kc < DP_ / 32; ++kc) {
      int ko = kc * 32 + quad * 8;
      short8 a0 = *(const short8*)(embP + (size_t)(m0 + l15) * DP_ + ko);
      short8 a1 = *(const short8*)(embP + (size_t)(m0 + 16 + l15) * DP_ + ko);
      short8 b0 = *(const short8*)(WihP + (size_t)(n0 + l15) * DP_ + ko);
      short8 b1 = *(const short8*)(WihP + (size_t)(n0 + 16 + l15) * DP_ + ko);
      acc[0][0] = MFMA(a0, b0, acc[0][0]);
      acc[0][1] = MFMA(a0, b1, acc[0][1]);
      acc[1][0] = MFMA(a1, b0, acc[1][0]);
      acc[1][1] = MFMA(a1, b1, acc[1][1]);
    }
    for (int mi = 0; mi < 2; ++mi)
      for (int ni = 0; ni < 2; ++ni)
        for (int r = 0; r < 4; ++r) {
          int m = m0 + mi * 16 + quad * 4 + r;
          int n = n0 + ni * 16 + l15;
          float v = acc[mi][ni][r] + bih[n] + bhh[n];
          Xg[(size_t)m * G4_ + n] = f2h(v);
        }
  }
}

// ---------------- K_scan: fence-free; B slice in TRUE VGPRs (full unroll) ----
#define SCAN_LDS (65536 + 4*32*17*4)
__global__ __launch_bounds__(256, 1) void k_scan(const float* __restrict__ Whh,
    const u16* __restrict__ Xg, u16* __restrict__ nodeH,
    float* __restrict__ nodeC, u16* __restrict__ hEx, int* meta)
{
  extern __shared__ char smem[];
  u16*   hst = (u16*)smem;                    // [32][1024] bf16, XOR-swizzled
  float* sG  = (float*)(smem + 65536);        // [4][32][17] gate pre-acts
  const int tid = threadIdx.x;
  const int g = tid >> 6, lane = tid & 63;
  const int l15 = lane & 15, quad = lane >> 4;
  const int n16 = blockIdx.x;
  int* flags = meta + MO_FLG;

  // B (gate g, cols n16*16..+16, all k) -> 128 persistent VGPRs (f32 -> bf16)
  short8 bf[32];
#pragma unroll
  for (int kc = 0; kc < 32; ++kc)
    bf[kc] = cvt8(Whh + ((size_t)(g * 1024 + n16 * 16 + l15)) * 1024 + kc * 32 + quad * 8);

  const int cb = g * 8 + (lane & 7);          // cell batch
  const int cp = lane >> 3;                   // cell col-pair
  const int c0 = n16 * 16 + cp * 2;

  float cst0 = 0.f, cst1 = 0.f;
  for (int t = 0; t < L_; ++t) {
    // prefetch this step's Xg gate inputs (independent of h(t-1))
    float xv[4][2];
    {
      const u16* xr = Xg + (size_t)(cb * 128 + t) * G4_;
#pragma unroll
      for (int gg = 0; gg < 4; ++gg)
#pragma unroll
        for (int u = 0; u < 2; ++u)
          xv[gg][u] = h2f(xr[gg * 1024 + c0 + u]);
    }
    floatx4 acc[2] = {};
    if (t > 0) {
      // stage h(t-1): 8192 u64 agent-coherent loads -> swizzled LDS
      const unsigned long long* src =
          (const unsigned long long*)(hEx + ((t - 1) & 1) * (B_ * H_));
#pragma unroll
      for (int ch = 0; ch < 2; ++ch) {
        unsigned long long tmp[16];
#pragma unroll
        for (int q = 0; q < 16; ++q)
          tmp[q] = __hip_atomic_load(src + (ch * 16 + q) * 256 + tid,
                                     __ATOMIC_RELAXED, __HIP_MEMORY_SCOPE_AGENT);
#pragma unroll
        for (int q = 0; q < 16; ++q) {
          int idx = (ch * 16 + q) * 256 + tid;
          int b = idx >> 8, g8 = idx & 255, gr = g8 >> 1;
          *(unsigned long long*)(hst + (b << 10) + ((gr ^ (b & 7)) << 3) + (g8 & 1) * 4) = tmp[q];
        }
      }
      __syncthreads();
#pragma unroll
      for (int kc = 0; kc < 32; ++kc) {       // FULL unroll -> bf[] stays in VGPRs
        int gr = (kc * 4 + quad) ^ (l15 & 7);
        short8 a0 = *(const short8*)(hst + (l15 << 10) + (gr << 3));
        short8 a1 = *(const short8*)(hst + ((16 + l15) << 10) + (gr << 3));
        acc[0] = MFMA(a0, bf[kc], acc[0]);
        acc[1] = MFMA(a1, bf[kc], acc[1]);
      }
    }
#pragma unroll
    for (int mt = 0; mt < 2; ++mt)
#pragma unroll
      for (int r = 0; r < 4; ++r)
        sG[(g * 32 + mt * 16 + quad * 4 + r) * 17 + l15] = acc[mt][r];
    __syncthreads();
    // cell update
    {
      float cc[2] = { cst0, cst1 };
      float hh[2];
#pragma unroll
      for (int u = 0; u < 2; ++u) {
        int col = cp * 2 + u;
        float iv = sG[(0 * 32 + cb) * 17 + col] + xv[0][u];
        float fv = sG[(1 * 32 + cb) * 17 + col] + xv[1][u];
        float gv = sG[(2 * 32 + cb) * 17 + col] + xv[2][u];
        float ov = sG[(3 * 32 + cb) * 17 + col] + xv[3][u];
        float c = sigf(fv) * cc[u] + sigf(iv) * tanh_(gv);
        float h = sigf(ov) * tanh_(c);
        cc[u] = c; hh[u] = h;
      }
      cst0 = cc[0]; cst1 = cc[1];
      unsigned pack = (unsigned)f2b(hh[0]) | ((unsigned)f2b(hh[1]) << 16);
      __hip_atomic_store((unsigned*)(hEx + (t & 1) * (B_ * H_)) + (cb << 9) + (c0 >> 1),
                         pack, __ATOMIC_RELAXED, __HIP_MEMORY_SCOPE_AGENT);
      *(unsigned*)(nodeH + (size_t)(cb * 129 + t) * H_ + c0) = pack;   // leaf archive
      *(float2*)(nodeC + (size_t)(cb * 129 + t) * H_ + c0) = make_float2(cc[0], cc[1]);
    }
    __syncthreads();   // drains vmcnt for all waves before flag release
    if (tid == 0)
      __hip_atomic_store(&flags[n16], t + 1, __ATOMIC_RELAXED, __HIP_MEMORY_SCOPE_AGENT);
    if (g == 0) {      // wave 0: one flag per lane, ballot across 64 blocks
      int it = 0;
      for (;;) {
        int v = __hip_atomic_load(&flags[lane], __ATOMIC_RELAXED, __HIP_MEMORY_SCOPE_AGENT);
        if (__all(v >= t + 1) || ++it >= SPIN_CAP) break;
        __builtin_amdgcn_s_sleep(1);
      }
    }
    __syncthreads();
  }
}

// ---------------- K_tree: O(n) Cartesian trees + O(n) level schedule ---------
__global__ void k_tree(const int* __restrict__ words, const int* __restrict__ lens,
                       int* meta)
{
  const int tid = threadIdx.x;
  __shared__ u16 sD[B_][L_];
  __shared__ short sL[B_][L_], sR[B_][L_];     // raw child indices, -1 = none
  __shared__ short sS[B_][130];                // stack (build, then preorder)
  __shared__ short sO[B_][L_];                 // preorder sequence
  __shared__ unsigned char sLev[B_][L_];       // height; 0 = Cartesian leaf
  __shared__ int sHist[132], sCur[132], sMaxLev;
  for (int i = tid; i < 132; i += 256) { sHist[i] = 0; sCur[i] = 0; }
  if (tid == 0) sMaxLev = 1;
  for (int i = tid; i < 256; i += 256) meta[MO_CNT + i] = 0;   // forest flags
  for (int i = tid; i < B_ * L_; i += 256) {   // parallel, coalesced init
    int b = i >> 7, t = i & 127;
    sD[b][t] = (u16)(words[i] % 1000);
    sL[b][t] = -1; sR[b][t] = -1; sLev[b][t] = 0;
  }
  __syncthreads();
  if (tid < B_) {
    const int b = tid;
    int len = lens[b];
    if (len < 2) len = 2;
    if (len > 128) len = 128;
    // --- 1. monotone-stack Cartesian min-tree (ties: leftmost is ancestor) ---
    int sp = 0;
    for (int i = 0; i < len; ++i) {
      int v = sD[b][i];
      int last = -1;
      while (sp > 0) {
        int top = sS[b][sp - 1];
        if ((int)sD[b][top] > v) { last = top; --sp; } else break;
      }
      sL[b][i] = (short)last;                  // last popped = left child of i
      if (sp > 0) sR[b][sS[b][sp - 1]] = (short)i; // i = (current) right child
      sS[b][sp++] = (short)i;
    }
    const int root = sS[b][0];                 // stack bottom = global min
    meta[MO_ROOT + b] = root;
    // --- 2a. preorder via explicit stack ---
    int cnt = 0, tp = 0;
    sS[b][tp++] = (short)root;
    while (tp > 0) {
      int p = sS[b][--tp];
      sO[b][cnt++] = (short)p;
      int l = sL[b][p], r = sR[b][p];
      if (l >= 0) sS[b][tp++] = (short)l;
      if (r >= 0) sS[b][tp++] = (short)r;
    }
    // --- 2b. reverse preorder: children processed before parents ---
    for (int k = cnt - 1; k >= 0; --k) {
      int p = sO[b][k];
      int l = sL[b][p], r = sR[b][p];
      if (l >= 0 || r >= 0) {
        int hl = (l >= 0) ? (int)sLev[b][l] : 0;
        int hr = (r >= 0) ? (int)sLev[b][r] : 0;
        sLev[b][p] = (unsigned char)(1 + (hl > hr ? hl : hr));
      }
    }
    atomicMax(&sMaxLev, (int)sLev[b][root]);
    for (int p = 0; p < len; ++p)
      if (sLev[b][p]) atomicAdd(&sHist[sLev[b][p]], 1);
  }
  __syncthreads();
  if (tid == 0) {
    int off2 = 0;
    for (int r = 1; r <= 128; ++r) {
      meta[MO_LSTART + r] = off2;
      sCur[r] = off2;
      meta[MO_LCOUNT + r] = sHist[r];
      off2 += sHist[r];
    }
    meta[MO_MAXLEV] = sMaxLev;
  }
  __syncthreads();
  if (tid < B_) {
    const int b = tid;
    int len = lens[b];
    if (len < 2) len = 2;
    if (len > 128) len = 128;
    for (int p = 0; p < len; ++p) if (sLev[b][p]) {
      int l = sL[b][p], r = sR[b][p];
      // encode: empty -> 128, Cartesian leaf -> raw index, compose -> 129+idx
      int le = (l < 0) ? 128 : (sLev[b][l] ? 129 + l : l);
      int re = (r < 0) ? 128 : (sLev[b][r] ? 129 + r : r);
      int idx = atomicAdd(&sCur[sLev[b][p]], 1);
      meta[MO_NODES + idx] = (b << 25) | (p << 18) | (le << 9) | re;
    }
  }
}

// ---------------- K_forest: weight-stationary, 4 cols/block, 256 blocks -----
// 256 blocks x 512 thr (8 waves, 1 block/CU). Block bcol owns h-cols
// 4*bcol..+3: 24 weight rows (6 gates x 4 cols) x K3072 bf16 = 144KB LDS,
// loaded ONCE. Halves blocks/XCD vs round 5 (64->32) -> halves the L2
// A-read amplification that bounded round 5; 128-node tiles (8 waves x 16
// nodes, each wave does BOTH n-frags from one A-load). Level barrier is now
// k_scan-style contention-free flags (one store per block, wave-0 ballot) --
// no 512-way atomic serialization. compC (4 cols) block-private plain
// stores; compH cross-block agent stores (proven). VGPR<=256 @ 2 waves/EU.
#define FOREST_LDS (147456 + 12288 + 512)     // wlds + sG + sInfo = 160256
__global__ __launch_bounds__(FTHREADS, 2) void k_forest(const u16* __restrict__ Wc,
    const float* __restrict__ bcomp, const u16* __restrict__ nodeH,
    const float* __restrict__ nodeC, u16* __restrict__ compH,
    float* __restrict__ compC, int* meta)
{
  extern __shared__ char smem[];
  u16*   wlds  = (u16*)smem;                       // [384 k-chunks][24 rows][8]
  float* sG    = (float*)(smem + 147456);          // [8 waves][16 nodes][24]
  int*   sInfo = (int*)(smem + 147456 + 12288);    // [128]
  const int bcol = blockIdx.x;                     // owns h-cols 4*bcol..+3
  const int tid = threadIdx.x;
  const int w = tid >> 6, lane = tid & 63;
  const int l15 = lane & 15, quad = lane >> 4;
  int* flg = meta + MO_CNT;                        // [256] per-block progress
  const int maxLev = meta[MO_MAXLEV];

  // ---- stage 24 weight rows into LDS once; LDS addr j*16B linear in tid
  //      (conflict-free ds_write_b128, round-5-proven pattern)
  for (int j = tid; j < 9216; j += FTHREADS) {
    int idx = j / 24, r24 = j - idx * 24;          // r24 = gate*4 + col
    int G = (r24 >> 2) * 1024 + bcol * 4 + (r24 & 3);
    *(short8*)(wlds + (size_t)j * 8) = *(const short8*)(Wc + (size_t)G * K3_ + idx * 8);
  }
  __syncthreads();

  for (int rd = 1; rd <= maxLev && rd <= 128; ++rd) {
    const int M = meta[MO_LCOUNT + rd];
    const int base = meta[MO_LSTART + rd];
    const int ntiles = (M + 127) >> 7;
    for (int tile = 0; tile < ntiles; ++tile) {
      __syncthreads();                             // guard sInfo/sG reuse
      if (tid < 128) {
        int j = tile * 128 + tid; if (j >= M) j = M - 1;
        sInfo[tid] = meta[MO_NODES + base + j];
      }
      __syncthreads();
      // --- MFMA: wave w = 16 nodes (lane l15), 2 n-frags (rows 0-15, 16-23)
      {
        int info = sInfo[w * 16 + l15];
        int b = (info >> 25) & 31, p = (info >> 18) & 127;
        int li = (info >> 9) & 0x1FF, ri = info & 0x1FF;
        const u16* A0 = (li <= 128) ? nodeH + ((size_t)(b * 129 + li) << 10)
                                    : compH + ((size_t)(b * 128 + li - 129) << 10);
        const u16* A1 = nodeH + ((size_t)(b * 129 + p) << 10);
        const u16* A2 = (ri <= 128) ? nodeH + ((size_t)(b * 129 + ri) << 10)
                                    : compH + ((size_t)(b * 128 + ri - 129) << 10);
        const u16* Aseg[3] = { A0, A1, A2 };
        floatx4 acc0 = {}, acc1 = {};
#pragma unroll
        for (int seg = 0; seg < 3; ++seg) {
          const u16* Ap = Aseg[seg] + quad * 8;
          const u16* B0 = wlds + ((size_t)((seg * 128 + quad) * 24 + l15)) * 8;
          const u16* B1 = wlds + ((size_t)((seg * 128 + quad) * 24 + 16 + (l15 & 7))) * 8;
#pragma unroll 4
          for (int kcL = 0; kcL < 32; ++kcL) {
            short8 av = *(const short8*)(Ap + kcL * 32);
            acc0 = MFMA(av, *(const short8*)(B0 + kcL * 768), acc0);
            acc1 = MFMA(av, *(const short8*)(B1 + kcL * 768), acc1);
          }
        }
        // D[m=quad*4+r][n=l15]; frag1 rows 16-23 valid only for l15<8
        float* sgw = sG + w * 384;
#pragma unroll
        for (int r = 0; r < 4; ++r)
          sgw[(quad * 4 + r) * 24 + l15] = acc0[r];
        if (l15 < 8)
#pragma unroll
          for (int r = 0; r < 4; ++r)
            sgw[(quad * 4 + r) * 24 + 16 + l15] = acc1[r];
      }
      __syncthreads();
      // --- epilogue: 512 threads = 128 nodes x 4 cols (block-local gates) --
      {
        int j_loc = tid >> 2, c = tid & 3;
        int j = tile * 128 + j_loc;
        if (j < M) {
          int info = sInfo[j_loc];
          int b = (info >> 25) & 31, p = (info >> 18) & 127;
          int li = (info >> 9) & 0x1FF, ri = info & 0x1FF;
          int hc = bcol * 4 + c;
          const float* gq = sG + (j_loc >> 4) * 384 + (j_loc & 15) * 24 + c;
          float gi  = gq[0]  + bcomp[hc];
          float gfl = gq[4]  + bcomp[H_ + hc];
          float gfx = gq[8]  + bcomp[2 * H_ + hc];
          float gfr = gq[12] + bcomp[3 * H_ + hc];
          float gu  = gq[16] + bcomp[4 * H_ + hc];
          float go  = gq[20] + bcomp[5 * H_ + hc];
          float cl  = (li <= 128) ? nodeC[(size_t)(b * 129 + li) * H_ + hc]
                                  : compC[(size_t)(b * 128 + li - 129) * H_ + hc];
          float cx  = nodeC[(size_t)(b * 129 + p) * H_ + hc];
          float cr2 = (ri <= 128) ? nodeC[(size_t)(b * 129 + ri) * H_ + hc]
                                  : compC[(size_t)(b * 128 + ri - 129) * H_ + hc];
          float cc = sigf(gi) * tanh_(gu) + sigf(gfl) * cl + sigf(gfx) * cx + sigf(gfr) * cr2;
          float hh = sigf(go) * tanh_(cc);
          __hip_atomic_store(&compH[(size_t)(b * 128 + p) * H_ + hc], f2b(hh),
                             __ATOMIC_RELAXED, __HIP_MEMORY_SCOPE_AGENT);
          compC[(size_t)(b * 128 + p) * H_ + hc] = cc;   // block-private cols
        }
      }
    }
    // ---- level barrier: contention-free flags (k_scan pattern, 256 blocks)
    __syncthreads();               // drains vmcnt for all waves before release
    if (tid == 0)
      __hip_atomic_store(&flg[bcol], rd, __ATOMIC_RELAXED, __HIP_MEMORY_SCOPE_AGENT);
    if (w == 0) {                  // wave 0: 4 flags per lane, ballot
      int it = 0;
      for (;;) {
        int f0 = __hip_atomic_load(&flg[lane],       __ATOMIC_RELAXED, __HIP_MEMORY_SCOPE_AGENT);
        int f1 = __hip_atomic_load(&flg[lane + 64],  __ATOMIC_RELAXED, __HIP_MEMORY_SCOPE_AGENT);
        int f2 = __hip_atomic_load(&flg[lane + 128], __ATOMIC_RELAXED, __HIP_MEMORY_SCOPE_AGENT);
        int f3 = __hip_atomic_load(&flg[lane + 192], __ATOMIC_RELAXED, __HIP_MEMORY_SCOPE_AGENT);
        bool ok = (f0 >= rd) && (f1 >= rd) && (f2 >= rd) && (f3 >= rd);
        if (__all(ok) || ++it >= SPIN_CAP2) break;
        __builtin_amdgcn_s_sleep(1);
      }
    }
    __syncthreads();
  }
}

// ---------------- K_round: fallback path (f32 weights, per-level dispatch) ---
template<int BF16B>
__global__ __launch_bounds__(384) void k_round(const void* __restrict__ Wc,
    const float* __restrict__ bcomp, const u16* __restrict__ nodeH,
    const float* __restrict__ nodeC, u16* __restrict__ compH,
    float* __restrict__ compC, const int* __restrict__ meta, int rd)
{
  const int M = meta[MO_LCOUNT + rd];
  if (M <= 0 || M > 2048) return;
  const int mb = blockIdx.x >> 6, hs = blockIdx.x & 63;
  if (mb * 64 >= M) return;
  const int base = meta[MO_LSTART + rd];
  const int tid = threadIdx.x;
  const int w = tid >> 6, lane = tid & 63;
  const int l15 = lane & 15, quad = lane >> 4;
  __shared__ float sG[6][64][17];
  __shared__ int sInfo[64];
  if (tid < 64) {
    int j = mb * 64 + tid; if (j >= M) j = M - 1;
    sInfo[tid] = meta[MO_NODES + base + j];
  }
  __syncthreads();
  {
    const u16* aseg[3][4];
#pragma unroll
    for (int mi = 0; mi < 4; ++mi) {
      int info = sInfo[mi * 16 + l15];
      int b = (info >> 25) & 31, p = (info >> 18) & 127;
      int li = (info >> 9) & 0x1FF, ri = info & 0x1FF;
      aseg[0][mi] = (li <= 128) ? nodeH + ((size_t)(b * 129 + li) << 10)
                                : compH + ((size_t)(b * 128 + li - 129) << 10);
      aseg[1][mi] = nodeH + ((size_t)(b * 129 + p) << 10);
      aseg[2][mi] = (ri <= 128) ? nodeH + ((size_t)(b * 129 + ri) << 10)
                                : compH + ((size_t)(b * 128 + ri - 129) << 10);
    }
    floatx4 acc[4] = {};
    const size_t brow = (size_t)(w * 1024 + hs * 16 + l15) * K3_;
    for (int kc = 0; kc < 96; ++kc) {
      int seg = kc >> 5, ko = (kc & 31) * 32 + quad * 8;
      short8 bfr;
      if (BF16B) bfr = *(const short8*)((const u16*)Wc + brow + kc * 32 + quad * 8);
      else       bfr = cvt8((const float*)Wc + brow + kc * 32 + quad * 8);
      acc[0] = MFMA(*(const short8*)(aseg[seg][0] + ko), bfr, acc[0]);
      acc[1] = MFMA(*(const short8*)(aseg[seg][1] + ko), bfr, acc[1]);
      acc[2] = MFMA(*(const short8*)(aseg[seg][2] + ko), bfr, acc[2]);
      acc[3] = MFMA(*(const short8*)(aseg[seg][3] + ko), bfr, acc[3]);
    }
#pragma unroll
    for (int mi = 0; mi < 4; ++mi)
#pragma unroll
      for (int r = 0; r < 4; ++r) sG[w][mi * 16 + quad * 4 + r][l15] = acc[mi][r];
  }
  __syncthreads();
  for (int idx = tid; idx < 1024; idx += 384) {
    int j_loc = idx >> 4, col = idx & 15;
    int j = mb * 64 + j_loc;
    if (j < M) {
      int info = sInfo[j_loc];
      int b = (info >> 25) & 31, p = (info >> 18) & 127;
      int li = (info >> 9) & 0x1FF, ri = info & 0x1FF;
      int hc = hs * 16 + col;
      float gi  = sG[0][j_loc][col] + bcomp[hc];
      float gfl = sG[1][j_loc][col] + bcomp[H_ + hc];
      float gfx = sG[2][j_loc][col] + bcomp[2 * H_ + hc];
      float gfr = sG[3][j_loc][col] + bcomp[3 * H_ + hc];
      float gu  = sG[4][j_loc][col] + bcomp[4 * H_ + hc];
      float go  = sG[5][j_loc][col] + bcomp[5 * H_ + hc];
      float cl  = (li <= 128) ? nodeC[(size_t)(b * 129 + li) * H_ + hc]
                              : compC[(size_t)(b * 128 + li - 129) * H_ + hc];
      float cx  = nodeC[(size_t)(b * 129 + p) * H_ + hc];
      float cr2 = (ri <= 128) ? nodeC[(size_t)(b * 129 + ri) * H_ + hc]
                              : compC[(size_t)(b * 128 + ri - 129) * H_ + hc];
      float c = sigf(gi) * tanh_(gu) + sigf(gfl) * cl + sigf(gfx) * cx + sigf(gfr) * cr2;
      float h = sigf(go) * tanh_(c);
      compH[(size_t)(b * 128 + p) * H_ + hc] = f2b(h);
      compC[(size_t)(b * 128 + p) * H_ + hc] = c;
    }
  }
}

// ---------------- K_out: emit root h then root c (f32) -----------------------
__global__ void k_out(const u16* __restrict__ compH, const float* __restrict__ compC,
                      const int* __restrict__ meta, float* __restrict__ out)
{
  int i = blockIdx.x * 256 + threadIdx.x;
  if (i >= 2 * B_ * H_) return;
  int part = i >> 15;
  int b = (i >> 10) & 31;
  int c = i & 1023;
  int root = meta[MO_ROOT + b] & 127;
  size_t rw = (size_t)(b * 128 + root) * H_ + c;
  out[i] = part ? compC[rw] : b2f(compH[rw]);
}

extern "C" void kernel_launch(void* const* d_in, const int* in_sizes, int n_in,
                              void* d_out, int out_size, void* d_ws, size_t ws_size,
                              hipStream_t stream)
{
  (void)in_sizes; (void)n_in; (void)out_size;
  const float* emb   = (const float*)d_in[0];
  const float* Wih   = (const float*)d_in[1];
  const float* Whh   = (const float*)d_in[2];
  const float* bih   = (const float*)d_in[3];
  const float* bhh   = (const float*)d_in[4];
  const float* Wcomp = (const float*)d_in[5];
  const float* bcomp = (const float*)d_in[6];
  const int* words   = (const int*)d_in[7];
  const int* lens    = (const int*)d_in[8];

  char* ws = (char*)d_ws;
  size_t off = 0;
  auto take = [&](size_t bytes) -> void* {
    void* p = ws + off; off += (bytes + 255) & ~(size_t)255; return p;
  };
  int*   meta  = (int*)  take((size_t)(512 + 4096 + 256) * 4);  // control first
  u16*   nodeH = (u16*)  take((size_t)B_ * 129 * H_ * 2);     // leaves + zero row
  float* nodeC = (float*)take((size_t)B_ * 129 * H_ * 4);
  u16*   embP  = (u16*)  take((size_t)B_ * L_ * DP_ * 2);
  u16*   WihP  = (u16*)  take((size_t)G4_ * DP_ * 2);
  u16*   hEx   = (u16*)  take((size_t)2 * B_ * H_ * 2);       // coherent h dbuf
  char*  xgreg = (char*) take((size_t)B_ * L_ * G4_ * 2);     // 33.5 MB
  u16*   Xg    = (u16*)  xgreg;
  u16*   compH = (u16*)  xgreg;                               // alias: dead Xg
  float* compC = (float*)(xgreg + (size_t)B_ * 128 * H_ * 2);
  // optional pre-converted bf16 Wcomp (37.75 MB) - only if ws has room
  u16* WcompB = nullptr;
  if (off + (size_t)6 * H_ * K3_ * 2 <= ws_size)
    WcompB = (u16*)take((size_t)6 * H_ * K3_ * 2);

  hipFuncSetAttribute((const void*)k_scan,
                      hipFuncAttributeMaxDynamicSharedMemorySize, SCAN_LDS);
  hipFuncSetAttribute((const void*)k_forest,
                      hipFuncAttributeMaxDynamicSharedMemorySize, FOREST_LDS);

  k_init<<<dim3(2048), dim3(256), 0, stream>>>(emb, Wih, Wcomp, embP, WihP,
                                               WcompB, nodeH, nodeC, meta);
  k_xg  <<<dim3(2048), dim3(256), 0, stream>>>(embP, WihP, bih, bhh, Xg);
  k_scan<<<dim3(64), dim3(256), SCAN_LDS, stream>>>(Whh, Xg, nodeH, nodeC, hEx, meta);
  k_tree<<<dim3(1), dim3(256), 0, stream>>>(words, lens, meta);
  if (WcompB) {
    k_forest<<<dim3(FGRID), dim3(FTHREADS), FOREST_LDS, stream>>>(WcompB, bcomp,
                                                nodeH, nodeC, compH, compC, meta);
  } else {
    for (int rd = 1; rd <= NROUNDS; ++rd) {
      int maxM = 32 * 128 / (rd + 1);
      if (maxM > 2048) maxM = 2048;
      int nb = ((maxM + 63) / 64) * 64;
      k_round<0><<<dim3(nb), dim3(384), 0, stream>>>(Wcomp, bcomp, nodeH, nodeC,
                                                     compH, compC, meta, rd);
    }
  }
  k_out<<<dim3(256), dim3(256), 0, stream>>>(compH, compC, meta, (float*)d_out);
}

// Round 8
// 1764.241 us; speedup vs baseline: 1.5928x; 1.0296x over previous
//
#include <hip/hip_runtime.h>

typedef unsigned short u16;
typedef __attribute__((ext_vector_type(8))) short short8;
typedef __attribute__((ext_vector_type(4))) float floatx4;

#define B_   32
#define L_   128
#define D_   300
#define DP_  320
#define H_   1024
#define G4_  4096
#define K3_  3072
#define NROUNDS 40        // fallback path only (f32 weights)

#define MO_MAXLEV 0
#define MO_ROOT   8
#define MO_LSTART 64
#define MO_LCOUNT 256
#define MO_FLG    448     // 64 scan barrier flags
#define MO_NODES  512
#define MO_CNT    4608    // 256 per-block level-progress flags (k_forest)
#define SPIN_CAP  500000
#define SPIN_CAP2 200000

#define FGRID 256         // k_forest blocks: one per 4 h-cols; ALL co-resident
#define FTHREADS 512

#define MFMA(a,b,c) __builtin_amdgcn_mfma_f32_16x16x32_bf16((a),(b),(c),0,0,0)

__device__ inline float b2f(u16 u){ union { unsigned int i; float f; } v; v.i = ((unsigned int)u) << 16; return v.f; }
__device__ inline u16 f2b(float f){ union { float f; unsigned int i; } v; v.f = f; unsigned int r = v.i + 0x7FFFu + ((v.i >> 16) & 1u); return (u16)(r >> 16); }
__device__ inline float h2f(u16 u){ union { _Float16 h; u16 s; } v; v.s = u; return (float)v.h; }
__device__ inline u16 f2h(float f){ union { _Float16 h; u16 s; } v; v.h = (_Float16)f; return v.s; }
__device__ inline float sigf(float x){ return 1.f / (1.f + __expf(-x)); }
__device__ inline float tanh_(float x){ return 1.f - 2.f / (__expf(2.f * x) + 1.f); }
__device__ inline short8 cvt8(const float* p){
  floatx4 a = *(const floatx4*)p, b = *(const floatx4*)(p + 4);
  short8 r;
  r[0]=(short)f2b(a[0]); r[1]=(short)f2b(a[1]); r[2]=(short)f2b(a[2]); r[3]=(short)f2b(a[3]);
  r[4]=(short)f2b(b[0]); r[5]=(short)f2b(b[1]); r[6]=(short)f2b(b[2]); r[7]=(short)f2b(b[3]);
  return r;
}

// ---------------- K_init: pad+convert inputs, zero state, optional Wcomp cvt -
__global__ void k_init(const float* __restrict__ emb, const float* __restrict__ Wih,
                       const float* __restrict__ Wcomp,
                       u16* __restrict__ embP, u16* __restrict__ WihP,
                       u16* __restrict__ WcompB,            // may be null
                       u16* __restrict__ nodeH, float* __restrict__ nodeC, int* meta)
{
  const int gtid = blockIdx.x * 256 + threadIdx.x;
  const int nT = 2048 * 256;
  if (gtid < 64) meta[MO_FLG + gtid] = 0;               // scan barrier flags
  for (int i = gtid; i < B_ * H_; i += nT) {            // zero row (leaf idx 128)
    int b = i >> 10, c = i & (H_ - 1);
    nodeH[(size_t)(b * 129 + 128) * H_ + c] = 0;
    nodeC[(size_t)(b * 129 + 128) * H_ + c] = 0.f;
  }
  for (int i = gtid; i < B_ * L_ * DP_; i += nT) {      // pad K 300 -> 320
    int r = i / DP_, k = i - r * DP_;
    embP[i] = (k < D_) ? f2b(emb[(size_t)r * D_ + k]) : (u16)0;
  }
  for (int i = gtid; i < G4_ * DP_; i += nT) {
    int r = i / DP_, k = i - r * DP_;
    WihP[i] = (k < D_) ? f2b(Wih[(size_t)r * D_ + k]) : (u16)0;
  }
  if (WcompB) {                                         // 6144x3072 f32 -> bf16
    for (int c = gtid; c < (6 * H_ * K3_) / 8; c += nT)
      *(short8*)(WcompB + (size_t)c * 8) = cvt8(Wcomp + (size_t)c * 8);
  }
}

// ---------------- K_xg: Xg[b*128+t][4096] = emb @ Wih^T + b_ih + b_hh (fp16) -
__global__ __launch_bounds__(256) void k_xg(const u16* __restrict__ embP,
    const u16* __restrict__ WihP, const float* __restrict__ bih,
    const float* __restrict__ bhh, u16* __restrict__ Xg)
{
  const int lane = threadIdx.x & 63, wave = threadIdx.x >> 6;
  const int l15 = lane & 15, quad = lane >> 4;
  const int gw = blockIdx.x * 4 + wave;
  for (int st = gw; st < 128 * 128; st += 2048 * 4) {
    int tm = st >> 7, tn = st & 127;
    int m0 = tm * 32, n0 = tn * 32;
    floatx4 acc[2][2] = {};
    for (int kc = 0; kc < DP_ / 32; ++kc) {
      int ko = kc * 32 + quad * 8;
      short8 a0 = *(const short8*)(embP + (size_t)(m0 + l15) * DP_ + ko);
      short8 a1 = *(const short8*)(embP + (size_t)(m0 + 16 + l15) * DP_ + ko);
      short8 b0 = *(const short8*)(WihP + (size_t)(n0 + l15) * DP_ + ko);
      short8 b1 = *(const short8*)(WihP + (size_t)(n0 + 16 + l15) * DP_ + ko);
      acc[0][0] = MFMA(a0, b0, acc[0][0]);
      acc[0][1] = MFMA(a0, b1, acc[0][1]);
      acc[1][0] = MFMA(a1, b0, acc[1][0]);
      acc[1][1] = MFMA(a1, b1, acc[1][1]);
    }
    for (int mi = 0; mi < 2; ++mi)
      for (int ni = 0; ni < 2; ++ni)
        for (int r = 0; r < 4; ++r) {
          int m = m0 + mi * 16 + quad * 4 + r;
          int n = n0 + ni * 16 + l15;
          float v = acc[mi][ni][r] + bih[n] + bhh[n];
          Xg[(size_t)m * G4_ + n] = f2h(v);
        }
  }
}

// ---------------- K_scan: proven agent-scope exchange (round-6 protocol) ----
// Changes vs round 6 (load ORDER only, protocol identical):
//   1. all 32 exchange u64 loads issued before any LDS write (one latency
//      round instead of two serialized rounds of 16)
//   2. chunk order rotated by block id (qq = (q+n16)&31) to spread the L3
//      hotspot of 64 blocks reading the same lines simultaneously
#define SCAN_LDS (65536 + 4*32*17*4)
__global__ __launch_bounds__(256, 1) void k_scan(const float* __restrict__ Whh,
    const u16* __restrict__ Xg, u16* __restrict__ nodeH,
    float* __restrict__ nodeC, u16* __restrict__ hEx, int* meta)
{
  extern __shared__ char smem[];
  u16*   hst = (u16*)smem;                    // [32][1024] bf16, XOR-swizzled
  float* sG  = (float*)(smem + 65536);        // [4][32][17] gate pre-acts
  const int tid = threadIdx.x;
  const int g = tid >> 6, lane = tid & 63;
  const int l15 = lane & 15, quad = lane >> 4;
  const int n16 = blockIdx.x;
  int* flags = meta + MO_FLG;

  // B (gate g, cols n16*16..+16, all k) -> 128 persistent VGPRs (f32 -> bf16)
  short8 bf[32];
#pragma unroll
  for (int kc = 0; kc < 32; ++kc)
    bf[kc] = cvt8(Whh + ((size_t)(g * 1024 + n16 * 16 + l15)) * 1024 + kc * 32 + quad * 8);

  const int cb = g * 8 + (lane & 7);          // cell batch
  const int cp = lane >> 3;                   // cell col-pair
  const int c0 = n16 * 16 + cp * 2;

  float cst0 = 0.f, cst1 = 0.f;
  for (int t = 0; t < L_; ++t) {
    // prefetch this step's Xg gate inputs (independent of h(t-1))
    float xv[4][2];
    {
      const u16* xr = Xg + (size_t)(cb * 128 + t) * G4_;
#pragma unroll
      for (int gg = 0; gg < 4; ++gg)
#pragma unroll
        for (int u = 0; u < 2; ++u)
          xv[gg][u] = h2f(xr[gg * 1024 + c0 + u]);
    }
    floatx4 acc[2] = {};
    if (t > 0) {
      // stage h(t-1): 8192 u64 agent-coherent loads -> swizzled LDS.
      // All 32 per-thread loads in flight at once; chunk order staggered
      // per block to avoid a 64-block L3 hotspot on the same lines.
      const unsigned long long* src =
          (const unsigned long long*)(hEx + ((t - 1) & 1) * (B_ * H_));
      unsigned long long tmp[32];
#pragma unroll
      for (int q = 0; q < 32; ++q) {
        int qq = (q + n16) & 31;
        tmp[q] = __hip_atomic_load(src + qq * 256 + tid,
                                   __ATOMIC_RELAXED, __HIP_MEMORY_SCOPE_AGENT);
      }
#pragma unroll
      for (int q = 0; q < 32; ++q) {
        int qq = (q + n16) & 31;
        int idx = qq * 256 + tid;
        int b = idx >> 8, g8 = idx & 255, gr = g8 >> 1;
        *(unsigned long long*)(hst + (b << 10) + ((gr ^ (b & 7)) << 3) + (g8 & 1) * 4) = tmp[q];
      }
      __syncthreads();
#pragma unroll
      for (int kc = 0; kc < 32; ++kc) {       // FULL unroll -> bf[] stays in VGPRs
        int gr = (kc * 4 + quad) ^ (l15 & 7);
        short8 a0 = *(const short8*)(hst + (l15 << 10) + (gr << 3));
        short8 a1 = *(const short8*)(hst + ((16 + l15) << 10) + (gr << 3));
        acc[0] = MFMA(a0, bf[kc], acc[0]);
        acc[1] = MFMA(a1, bf[kc], acc[1]);
      }
    }
#pragma unroll
    for (int mt = 0; mt < 2; ++mt)
#pragma unroll
      for (int r = 0; r < 4; ++r)
        sG[(g * 32 + mt * 16 + quad * 4 + r) * 17 + l15] = acc[mt][r];
    __syncthreads();
    // cell update
    {
      float cc[2] = { cst0, cst1 };
      float hh[2];
#pragma unroll
      for (int u = 0; u < 2; ++u) {
        int col = cp * 2 + u;
        float iv = sG[(0 * 32 + cb) * 17 + col] + xv[0][u];
        float fv = sG[(1 * 32 + cb) * 17 + col] + xv[1][u];
        float gv = sG[(2 * 32 + cb) * 17 + col] + xv[2][u];
        float ov = sG[(3 * 32 + cb) * 17 + col] + xv[3][u];
        float c = sigf(fv) * cc[u] + sigf(iv) * tanh_(gv);
        float h = sigf(ov) * tanh_(c);
        cc[u] = c; hh[u] = h;
      }
      cst0 = cc[0]; cst1 = cc[1];
      unsigned pack = (unsigned)f2b(hh[0]) | ((unsigned)f2b(hh[1]) << 16);
      __hip_atomic_store((unsigned*)(hEx + (t & 1) * (B_ * H_)) + (cb << 9) + (c0 >> 1),
                         pack, __ATOMIC_RELAXED, __HIP_MEMORY_SCOPE_AGENT);
      *(unsigned*)(nodeH + (size_t)(cb * 129 + t) * H_ + c0) = pack;   // leaf archive
      *(float2*)(nodeC + (size_t)(cb * 129 + t) * H_ + c0) = make_float2(cc[0], cc[1]);
    }
    __syncthreads();   // drains vmcnt for all waves before flag release
    if (tid == 0)
      __hip_atomic_store(&flags[n16], t + 1, __ATOMIC_RELAXED, __HIP_MEMORY_SCOPE_AGENT);
    if (g == 0) {      // wave 0: one flag per lane, ballot across 64 blocks
      int it = 0;
      for (;;) {
        int v = __hip_atomic_load(&flags[lane], __ATOMIC_RELAXED, __HIP_MEMORY_SCOPE_AGENT);
        if (__all(v >= t + 1) || ++it >= SPIN_CAP) break;
        __builtin_amdgcn_s_sleep(1);
      }
    }
    __syncthreads();
  }
}

// ---------------- K_tree: O(n) Cartesian trees + O(n) level schedule ---------
__global__ void k_tree(const int* __restrict__ words, const int* __restrict__ lens,
                       int* meta)
{
  const int tid = threadIdx.x;
  __shared__ u16 sD[B_][L_];
  __shared__ short sL[B_][L_], sR[B_][L_];     // raw child indices, -1 = none
  __shared__ short sS[B_][130];                // stack (build, then preorder)
  __shared__ short sO[B_][L_];                 // preorder sequence
  __shared__ unsigned char sLev[B_][L_];       // height; 0 = Cartesian leaf
  __shared__ int sHist[132], sCur[132], sMaxLev;
  for (int i = tid; i < 132; i += 256) { sHist[i] = 0; sCur[i] = 0; }
  if (tid == 0) sMaxLev = 1;
  for (int i = tid; i < 256; i += 256) meta[MO_CNT + i] = 0;   // forest flags
  for (int i = tid; i < B_ * L_; i += 256) {   // parallel, coalesced init
    int b = i >> 7, t = i & 127;
    sD[b][t] = (u16)(words[i] % 1000);
    sL[b][t] = -1; sR[b][t] = -1; sLev[b][t] = 0;
  }
  __syncthreads();
  if (tid < B_) {
    const int b = tid;
    int len = lens[b];
    if (len < 2) len = 2;
    if (len > 128) len = 128;
    // --- 1. monotone-stack Cartesian min-tree (ties: leftmost is ancestor) ---
    int sp = 0;
    for (int i = 0; i < len; ++i) {
      int v = sD[b][i];
      int last = -1;
      while (sp > 0) {
        int top = sS[b][sp - 1];
        if ((int)sD[b][top] > v) { last = top; --sp; } else break;
      }
      sL[b][i] = (short)last;                  // last popped = left child of i
      if (sp > 0) sR[b][sS[b][sp - 1]] = (short)i; // i = (current) right child
      sS[b][sp++] = (short)i;
    }
    const int root = sS[b][0];                 // stack bottom = global min
    meta[MO_ROOT + b] = root;
    // --- 2a. preorder via explicit stack ---
    int cnt = 0, tp = 0;
    sS[b][tp++] = (short)root;
    while (tp > 0) {
      int p = sS[b][--tp];
      sO[b][cnt++] = (short)p;
      int l = sL[b][p], r = sR[b][p];
      if (l >= 0) sS[b][tp++] = (short)l;
      if (r >= 0) sS[b][tp++] = (short)r;
    }
    // --- 2b. reverse preorder: children processed before parents ---
    for (int k = cnt - 1; k >= 0; --k) {
      int p = sO[b][k];
      int l = sL[b][p], r = sR[b][p];
      if (l >= 0 || r >= 0) {
        int hl = (l >= 0) ? (int)sLev[b][l] : 0;
        int hr = (r >= 0) ? (int)sLev[b][r] : 0;
        sLev[b][p] = (unsigned char)(1 + (hl > hr ? hl : hr));
      }
    }
    atomicMax(&sMaxLev, (int)sLev[b][root]);
    for (int p = 0; p < len; ++p)
      if (sLev[b][p]) atomicAdd(&sHist[sLev[b][p]], 1);
  }
  __syncthreads();
  if (tid == 0) {
    int off2 = 0;
    for (int r = 1; r <= 128; ++r) {
      meta[MO_LSTART + r] = off2;
      sCur[r] = off2;
      meta[MO_LCOUNT + r] = sHist[r];
      off2 += sHist[r];
    }
    meta[MO_MAXLEV] = sMaxLev;
  }
  __syncthreads();
  if (tid < B_) {
    const int b = tid;
    int len = lens[b];
    if (len < 2) len = 2;
    if (len > 128) len = 128;
    for (int p = 0; p < len; ++p) if (sLev[b][p]) {
      int l = sL[b][p], r = sR[b][p];
      // encode: empty -> 128, Cartesian leaf -> raw index, compose -> 129+idx
      int le = (l < 0) ? 128 : (sLev[b][l] ? 129 + l : l);
      int re = (r < 0) ? 128 : (sLev[b][r] ? 129 + r : r);
      int idx = atomicAdd(&sCur[sLev[b][p]], 1);
      meta[MO_NODES + idx] = (b << 25) | (p << 18) | (le << 9) | re;
    }
  }
}

// ---------------- K_forest: weight-stationary, 4 cols/block, 256 blocks -----
#define FOREST_LDS (147456 + 12288 + 512)     // wlds + sG + sInfo = 160256
__global__ __launch_bounds__(FTHREADS, 2) void k_forest(const u16* __restrict__ Wc,
    const float* __restrict__ bcomp, const u16* __restrict__ nodeH,
    const float* __restrict__ nodeC, u16* __restrict__ compH,
    float* __restrict__ compC, int* meta)
{
  extern __shared__ char smem[];
  u16*   wlds  = (u16*)smem;                       // [384 k-chunks][24 rows][8]
  float* sG    = (float*)(smem + 147456);          // [8 waves][16 nodes][24]
  int*   sInfo = (int*)(smem + 147456 + 12288);    // [128]
  const int bcol = blockIdx.x;                     // owns h-cols 4*bcol..+3
  const int tid = threadIdx.x;
  const int w = tid >> 6, lane = tid & 63;
  const int l15 = lane & 15, quad = lane >> 4;
  int* flg = meta + MO_CNT;                        // [256] per-block progress
  const int maxLev = meta[MO_MAXLEV];

  // ---- stage 24 weight rows into LDS once; LDS addr j*16B linear in tid
  for (int j = tid; j < 9216; j += FTHREADS) {
    int idx = j / 24, r24 = j - idx * 24;          // r24 = gate*4 + col
    int G = (r24 >> 2) * 1024 + bcol * 4 + (r24 & 3);
    *(short8*)(wlds + (size_t)j * 8) = *(const short8*)(Wc + (size_t)G * K3_ + idx * 8);
  }
  __syncthreads();

  for (int rd = 1; rd <= maxLev && rd <= 128; ++rd) {
    const int M = meta[MO_LCOUNT + rd];
    const int base = meta[MO_LSTART + rd];
    const int ntiles = (M + 127) >> 7;
    for (int tile = 0; tile < ntiles; ++tile) {
      __syncthreads();                             // guard sInfo/sG reuse
      if (tid < 128) {
        int j = tile * 128 + tid; if (j >= M) j = M - 1;
        sInfo[tid] = meta[MO_NODES + base + j];
      }
      __syncthreads();
      // --- MFMA: wave w = 16 nodes (lane l15), 2 n-frags (rows 0-15, 16-23)
      {
        int info = sInfo[w * 16 + l15];
        int b = (info >> 25) & 31, p = (info >> 18) & 127;
        int li = (info >> 9) & 0x1FF, ri = info & 0x1FF;
        const u16* A0 = (li <= 128) ? nodeH + ((size_t)(b * 129 + li) << 10)
                                    : compH + ((size_t)(b * 128 + li - 129) << 10);
        const u16* A1 = nodeH + ((size_t)(b * 129 + p) << 10);
        const u16* A2 = (ri <= 128) ? nodeH + ((size_t)(b * 129 + ri) << 10)
                                    : compH + ((size_t)(b * 128 + ri - 129) << 10);
        const u16* Aseg[3] = { A0, A1, A2 };
        floatx4 acc0 = {}, acc1 = {};
#pragma unroll
        for (int seg = 0; seg < 3; ++seg) {
          const u16* Ap = Aseg[seg] + quad * 8;
          const u16* B0 = wlds + ((size_t)((seg * 128 + quad) * 24 + l15)) * 8;
          const u16* B1 = wlds + ((size_t)((seg * 128 + quad) * 24 + 16 + (l15 & 7))) * 8;
#pragma unroll 4
          for (int kcL = 0; kcL < 32; ++kcL) {
            short8 av = *(const short8*)(Ap + kcL * 32);
            acc0 = MFMA(av, *(const short8*)(B0 + kcL * 768), acc0);
            acc1 = MFMA(av, *(const short8*)(B1 + kcL * 768), acc1);
          }
        }
        // D[m=quad*4+r][n=l15]; frag1 rows 16-23 valid only for l15<8
        float* sgw = sG + w * 384;
#pragma unroll
        for (int r = 0; r < 4; ++r)
          sgw[(quad * 4 + r) * 24 + l15] = acc0[r];
        if (l15 < 8)
#pragma unroll
          for (int r = 0; r < 4; ++r)
            sgw[(quad * 4 + r) * 24 + 16 + l15] = acc1[r];
      }
      __syncthreads();
      // --- epilogue: 512 threads = 128 nodes x 4 cols (block-local gates) --
      {
        int j_loc = tid >> 2, c = tid & 3;
        int j = tile * 128 + j_loc;
        if (j < M) {
          int info = sInfo[j_loc];
          int b = (info >> 25) & 31, p = (info >> 18) & 127;
          int li = (info >> 9) & 0x1FF, ri = info & 0x1FF;
          int hc = bcol * 4 + c;
          const float* gq = sG + (j_loc >> 4) * 384 + (j_loc & 15) * 24 + c;
          float gi  = gq[0]  + bcomp[hc];
          float gfl = gq[4]  + bcomp[H_ + hc];
          float gfx = gq[8]  + bcomp[2 * H_ + hc];
          float gfr = gq[12] + bcomp[3 * H_ + hc];
          float gu  = gq[16] + bcomp[4 * H_ + hc];
          float go  = gq[20] + bcomp[5 * H_ + hc];
          float cl  = (li <= 128) ? nodeC[(size_t)(b * 129 + li) * H_ + hc]
                                  : compC[(size_t)(b * 128 + li - 129) * H_ + hc];
          float cx  = nodeC[(size_t)(b * 129 + p) * H_ + hc];
          float cr2 = (ri <= 128) ? nodeC[(size_t)(b * 129 + ri) * H_ + hc]
                                  : compC[(size_t)(b * 128 + ri - 129) * H_ + hc];
          float cc = sigf(gi) * tanh_(gu) + sigf(gfl) * cl + sigf(gfx) * cx + sigf(gfr) * cr2;
          float hh = sigf(go) * tanh_(cc);
          __hip_atomic_store(&compH[(size_t)(b * 128 + p) * H_ + hc], f2b(hh),
                             __ATOMIC_RELAXED, __HIP_MEMORY_SCOPE_AGENT);
          compC[(size_t)(b * 128 + p) * H_ + hc] = cc;   // block-private cols
        }
      }
    }
    // ---- level barrier: contention-free flags (k_scan pattern, 256 blocks)
    __syncthreads();               // drains vmcnt for all waves before release
    if (tid == 0)
      __hip_atomic_store(&flg[bcol], rd, __ATOMIC_RELAXED, __HIP_MEMORY_SCOPE_AGENT);
    if (w == 0) {                  // wave 0: 4 flags per lane, ballot
      int it = 0;
      for (;;) {
        int f0 = __hip_atomic_load(&flg[lane],       __ATOMIC_RELAXED, __HIP_MEMORY_SCOPE_AGENT);
        int f1 = __hip_atomic_load(&flg[lane + 64],  __ATOMIC_RELAXED, __HIP_MEMORY_SCOPE_AGENT);
        int f2 = __hip_atomic_load(&flg[lane + 128], __ATOMIC_RELAXED, __HIP_MEMORY_SCOPE_AGENT);
        int f3 = __hip_atomic_load(&flg[lane + 192], __ATOMIC_RELAXED, __HIP_MEMORY_SCOPE_AGENT);
        bool ok = (f0 >= rd) && (f1 >= rd) && (f2 >= rd) && (f3 >= rd);
        if (__all(ok) || ++it >= SPIN_CAP2) break;
        __builtin_amdgcn_s_sleep(1);
      }
    }
    __syncthreads();
  }
}

// ---------------- K_round: fallback path (f32 weights, per-level dispatch) ---
template<int BF16B>
__global__ __launch_bounds__(384) void k_round(const void* __restrict__ Wc,
    const float* __restrict__ bcomp, const u16* __restrict__ nodeH,
    const float* __restrict__ nodeC, u16* __restrict__ compH,
    float* __restrict__ compC, const int* __restrict__ meta, int rd)
{
  const int M = meta[MO_LCOUNT + rd];
  if (M <= 0 || M > 2048) return;
  const int mb = blockIdx.x >> 6, hs = blockIdx.x & 63;
  if (mb * 64 >= M) return;
  const int base = meta[MO_LSTART + rd];
  const int tid = threadIdx.x;
  const int w = tid >> 6, lane = tid & 63;
  const int l15 = lane & 15, quad = lane >> 4;
  __shared__ float sG[6][64][17];
  __shared__ int sInfo[64];
  if (tid < 64) {
    int j = mb * 64 + tid; if (j >= M) j = M - 1;
    sInfo[tid] = meta[MO_NODES + base + j];
  }
  __syncthreads();
  {
    const u16* aseg[3][4];
#pragma unroll
    for (int mi = 0; mi < 4; ++mi) {
      int info = sInfo[mi * 16 + l15];
      int b = (info >> 25) & 31, p = (info >> 18) & 127;
      int li = (info >> 9) & 0x1FF, ri = info & 0x1FF;
      aseg[0][mi] = (li <= 128) ? nodeH + ((size_t)(b * 129 + li) << 10)
                                : compH + ((size_t)(b * 128 + li - 129) << 10);
      aseg[1][mi] = nodeH + ((size_t)(b * 129 + p) << 10);
      aseg[2][mi] = (ri <= 128) ? nodeH + ((size_t)(b * 129 + ri) << 10)
                                : compH + ((size_t)(b * 128 + ri - 129) << 10);
    }
    floatx4 acc[4] = {};
    const size_t brow = (size_t)(w * 1024 + hs * 16 + l15) * K3_;
    for (int kc = 0; kc < 96; ++kc) {
      int seg = kc >> 5, ko = (kc & 31) * 32 + quad * 8;
      short8 bfr;
      if (BF16B) bfr = *(const short8*)((const u16*)Wc + brow + kc * 32 + quad * 8);
      else       bfr = cvt8((const float*)Wc + brow + kc * 32 + quad * 8);
      acc[0] = MFMA(*(const short8*)(aseg[seg][0] + ko), bfr, acc[0]);
      acc[1] = MFMA(*(const short8*)(aseg[seg][1] + ko), bfr, acc[1]);
      acc[2] = MFMA(*(const short8*)(aseg[seg][2] + ko), bfr, acc[2]);
      acc[3] = MFMA(*(const short8*)(aseg[seg][3] + ko), bfr, acc[3]);
    }
#pragma unroll
    for (int mi = 0; mi < 4; ++mi)
#pragma unroll
      for (int r = 0; r < 4; ++r) sG[w][mi * 16 + quad * 4 + r][l15] = acc[mi][r];
  }
  __syncthreads();
  for (int idx = tid; idx < 1024; idx += 384) {
    int j_loc = idx >> 4, col = idx & 15;
    int j = mb * 64 + j_loc;
    if (j < M) {
      int info = sInfo[j_loc];
      int b = (info >> 25) & 31, p = (info >> 18) & 127;
      int li = (info >> 9) & 0x1FF, ri = info & 0x1FF;
      int hc = hs * 16 + col;
      float gi  = sG[0][j_loc][col] + bcomp[hc];
      float gfl = sG[1][j_loc][col] + bcomp[H_ + hc];
      float gfx = sG[2][j_loc][col] + bcomp[2 * H_ + hc];
      float gfr = sG[3][j_loc][col] + bcomp[3 * H_ + hc];
      float gu  = sG[4][j_loc][col] + bcomp[4 * H_ + hc];
      float go  = sG[5][j_loc][col] + bcomp[5 * H_ + hc];
      float cl  = (li <= 128) ? nodeC[(size_t)(b * 129 + li) * H_ + hc]
                              : compC[(size_t)(b * 128 + li - 129) * H_ + hc];
      float cx  = nodeC[(size_t)(b * 129 + p) * H_ + hc];
      float cr2 = (ri <= 128) ? nodeC[(size_t)(b * 129 + ri) * H_ + hc]
                              : compC[(size_t)(b * 128 + ri - 129) * H_ + hc];
      float c = sigf(gi) * tanh_(gu) + sigf(gfl) * cl + sigf(gfx) * cx + sigf(gfr) * cr2;
      float h = sigf(go) * tanh_(c);
      compH[(size_t)(b * 128 + p) * H_ + hc] = f2b(h);
      compC[(size_t)(b * 128 + p) * H_ + hc] = c;
    }
  }
}

// ---------------- K_out: emit root h then root c (f32) -----------------------
__global__ void k_out(const u16* __restrict__ compH, const float* __restrict__ compC,
                      const int* __restrict__ meta, float* __restrict__ out)
{
  int i = blockIdx.x * 256 + threadIdx.x;
  if (i >= 2 * B_ * H_) return;
  int part = i >> 15;
  int b = (i >> 10) & 31;
  int c = i & 1023;
  int root = meta[MO_ROOT + b] & 127;
  size_t rw = (size_t)(b * 128 + root) * H_ + c;
  out[i] = part ? compC[rw] : b2f(compH[rw]);
}

extern "C" void kernel_launch(void* const* d_in, const int* in_sizes, int n_in,
                              void* d_out, int out_size, void* d_ws, size_t ws_size,
                              hipStream_t stream)
{
  (void)in_sizes; (void)n_in; (void)out_size;
  const float* emb   = (const float*)d_in[0];
  const float* Wih   = (const float*)d_in[1];
  const float* Whh   = (const float*)d_in[2];
  const float* bih   = (const float*)d_in[3];
  const float* bhh   = (const float*)d_in[4];
  const float* Wcomp = (const float*)d_in[5];
  const float* bcomp = (const float*)d_in[6];
  const int* words   = (const int*)d_in[7];
  const int* lens    = (const int*)d_in[8];

  char* ws = (char*)d_ws;
  size_t off = 0;
  auto take = [&](size_t bytes) -> void* {
    void* p = ws + off; off += (bytes + 255) & ~(size_t)255; return p;
  };
  int*   meta  = (int*)  take((size_t)(512 + 4096 + 256) * 4);  // control first
  u16*   nodeH = (u16*)  take((size_t)B_ * 129 * H_ * 2);     // leaves + zero row
  float* nodeC = (float*)take((size_t)B_ * 129 * H_ * 4);
  u16*   embP  = (u16*)  take((size_t)B_ * L_ * DP_ * 2);
  u16*   WihP  = (u16*)  take((size_t)G4_ * DP_ * 2);
  u16*   hEx   = (u16*)  take((size_t)2 * B_ * H_ * 2);       // coherent h dbuf
  char*  xgreg = (char*) take((size_t)B_ * L_ * G4_ * 2);     // 33.5 MB
  u16*   Xg    = (u16*)  xgreg;
  u16*   compH = (u16*)  xgreg;                               // alias: dead Xg
  float* compC = (float*)(xgreg + (size_t)B_ * 128 * H_ * 2);
  // optional pre-converted bf16 Wcomp (37.75 MB) - only if ws has room
  u16* WcompB = nullptr;
  if (off + (size_t)6 * H_ * K3_ * 2 <= ws_size)
    WcompB = (u16*)take((size_t)6 * H_ * K3_ * 2);

  hipFuncSetAttribute((const void*)k_scan,
                      hipFuncAttributeMaxDynamicSharedMemorySize, SCAN_LDS);
  hipFuncSetAttribute((const void*)k_forest,
                      hipFuncAttributeMaxDynamicSharedMemorySize, FOREST_LDS);

  k_init<<<dim3(2048), dim3(256), 0, stream>>>(emb, Wih, Wcomp, embP, WihP,
                                               WcompB, nodeH, nodeC, meta);
  k_xg  <<<dim3(2048), dim3(256), 0, stream>>>(embP, WihP, bih, bhh, Xg);
  k_scan<<<dim3(64), dim3(256), SCAN_LDS, stream>>>(Whh, Xg, nodeH, nodeC, hEx, meta);
  k_tree<<<dim3(1), dim3(256), 0, stream>>>(words, lens, meta);
  if (WcompB) {
    k_forest<<<dim3(FGRID), dim3(FTHREADS), FOREST_LDS, stream>>>(WcompB, bcomp,
                                                nodeH, nodeC, compH, compC, meta);
  } else {
    for (int rd = 1; rd <= NROUNDS; ++rd) {
      int maxM = 32 * 128 / (rd + 1);
      if (maxM > 2048) maxM = 2048;
      int nb = ((maxM + 63) / 64) * 64;
      k_round<0><<<dim3(nb), dim3(384), 0, stream>>>(Wcomp, bcomp, nodeH, nodeC,
                                                     compH, compC, meta, rd);
    }
  }
  k_out<<<dim3(256), dim3(256), 0, stream>>>(compH, compC, meta, (float*)d_out);
}

// Round 9
// 1712.029 us; speedup vs baseline: 1.6414x; 1.0305x over previous
//
#include <hip/hip_runtime.h>

typedef unsigned short u16;
typedef __attribute__((ext_vector_type(8))) short short8;
typedef __attribute__((ext_vector_type(4))) float floatx4;

#define B_   32
#define L_   128
#define D_   300
#define DP_  320
#define H_   1024
#define G4_  4096
#define K3_  3072
#define NROUNDS 40        // fallback path only (f32 weights)

#define MO_MAXLEV 0
#define MO_ROOT   8
#define MO_LSTART 64
#define MO_LCOUNT 256
#define MO_FLG    448     // legacy (unused by new scan)
#define MO_NODES  512
#define MO_CNT    4608    // 256 per-block level-progress flags (k_forest)
#define MO_SFLG   4864    // 32 scan flags, PADDED one per 64B line (x16 ints)
#define SPIN_CAP  500000
#define SPIN_CAP2 200000

#define FGRID 256         // k_forest blocks: one per 4 h-cols; ALL co-resident
#define FTHREADS 512

#define MFMA(a,b,c) __builtin_amdgcn_mfma_f32_16x16x32_bf16((a),(b),(c),0,0,0)

__device__ inline float b2f(u16 u){ union { unsigned int i; float f; } v; v.i = ((unsigned int)u) << 16; return v.f; }
__device__ inline u16 f2b(float f){ union { float f; unsigned int i; } v; v.f = f; unsigned int r = v.i + 0x7FFFu + ((v.i >> 16) & 1u); return (u16)(r >> 16); }
__device__ inline float h2f(u16 u){ union { _Float16 h; u16 s; } v; v.s = u; return (float)v.h; }
__device__ inline u16 f2h(float f){ union { _Float16 h; u16 s; } v; v.h = (_Float16)f; return v.s; }
__device__ inline float sigf(float x){ return 1.f / (1.f + __expf(-x)); }
__device__ inline float tanh_(float x){ return 1.f - 2.f / (__expf(2.f * x) + 1.f); }
__device__ inline short8 cvt8(const float* p){
  floatx4 a = *(const floatx4*)p, b = *(const floatx4*)(p + 4);
  short8 r;
  r[0]=(short)f2b(a[0]); r[1]=(short)f2b(a[1]); r[2]=(short)f2b(a[2]); r[3]=(short)f2b(a[3]);
  r[4]=(short)f2b(b[0]); r[5]=(short)f2b(b[1]); r[6]=(short)f2b(b[2]); r[7]=(short)f2b(b[3]);
  return r;
}

// ---------------- K_init: pad+convert inputs, zero state, optional Wcomp cvt -
__global__ void k_init(const float* __restrict__ emb, const float* __restrict__ Wih,
                       const float* __restrict__ Wcomp,
                       u16* __restrict__ embP, u16* __restrict__ WihP,
                       u16* __restrict__ WcompB,            // may be null
                       u16* __restrict__ nodeH, float* __restrict__ nodeC, int* meta)
{
  const int gtid = blockIdx.x * 256 + threadIdx.x;
  const int nT = 2048 * 256;
  if (gtid < 64) meta[MO_FLG + gtid] = 0;               // legacy flags
  if (gtid < 512) meta[MO_SFLG + gtid] = 0;             // padded scan flags
  for (int i = gtid; i < B_ * H_; i += nT) {            // zero row (leaf idx 128)
    int b = i >> 10, c = i & (H_ - 1);
    nodeH[(size_t)(b * 129 + 128) * H_ + c] = 0;
    nodeC[(size_t)(b * 129 + 128) * H_ + c] = 0.f;
  }
  for (int i = gtid; i < B_ * L_ * DP_; i += nT) {      // pad K 300 -> 320
    int r = i / DP_, k = i - r * DP_;
    embP[i] = (k < D_) ? f2b(emb[(size_t)r * D_ + k]) : (u16)0;
  }
  for (int i = gtid; i < G4_ * DP_; i += nT) {
    int r = i / DP_, k = i - r * DP_;
    WihP[i] = (k < D_) ? f2b(Wih[(size_t)r * D_ + k]) : (u16)0;
  }
  if (WcompB) {                                         // 6144x3072 f32 -> bf16
    for (int c = gtid; c < (6 * H_ * K3_) / 8; c += nT)
      *(short8*)(WcompB + (size_t)c * 8) = cvt8(Wcomp + (size_t)c * 8);
  }
}

// ---------------- K_xg: Xg[b*128+t][4096] = emb @ Wih^T + b_ih + b_hh (fp16) -
__global__ __launch_bounds__(256) void k_xg(const u16* __restrict__ embP,
    const u16* __restrict__ WihP, const float* __restrict__ bih,
    const float* __restrict__ bhh, u16* __restrict__ Xg)
{
  const int lane = threadIdx.x & 63, wave = threadIdx.x >> 6;
  const int l15 = lane & 15, quad = lane >> 4;
  const int gw = blockIdx.x * 4 + wave;
  for (int st = gw; st < 128 * 128; st += 2048 * 4) {
    int tm = st >> 7, tn = st & 127;
    int m0 = tm * 32, n0 = tn * 32;
    floatx4 acc[2][2] = {};
    for (int kc = 0; kc < DP_ / 32; ++kc) {
      int ko = kc * 32 + quad * 8;
      short8 a0 = *(const short8*)(embP + (size_t)(m0 + l15) * DP_ + ko);
      short8 a1 = *(const short8*)(embP + (size_t)(m0 + 16 + l15) * DP_ + ko);
      short8 b0 = *(const short8*)(WihP + (size_t)(n0 + l15) * DP_ + ko);
      short8 b1 = *(const short8*)(WihP + (size_t)(n0 + 16 + l15) * DP_ + ko);
      acc[0][0] = MFMA(a0, b0, acc[0][0]);
      acc[0][1] = MFMA(a0, b1, acc[0][1]);
      acc[1][0] = MFMA(a1, b0, acc[1][0]);
      acc[1][1] = MFMA(a1, b1, acc[1][1]);
    }
    for (int mi = 0; mi < 2; ++mi)
      for (int ni = 0; ni < 2; ++ni)
        for (int r = 0; r < 4; ++r) {
          int m = m0 + mi * 16 + quad * 4 + r;
          int n = n0 + ni * 16 + l15;
          float v = acc[mi][ni][r] + bih[n] + bhh[n];
          Xg[(size_t)m * G4_ + n] = f2h(v);
        }
  }
}

// ---------------- K_scan: 32 blocks x 8 waves; agent exchange (proven) ------
// vs round 8 (protocol identical, shape changed):
//  - 32 blocks x 512 thr (was 64x256): halves total L3 broadcast traffic
//    (2MB/step), 8 waves hide the 64KB load latency better. Block owns 32
//    h-cols x 4 gates; per-wave weights still 16 rows x K1024 = 128 VGPRs.
//  - flags PADDED one per 64B line (sflg[b*16]): poll = 32 blocks x 32 lanes
//    over 32 distinct lines (32 req/line vs ~1024/line before).
#define SCAN_LDS (65536 + 128*36*4)
__global__ __launch_bounds__(512, 1) void k_scan(const float* __restrict__ Whh,
    const u16* __restrict__ Xg, u16* __restrict__ nodeH,
    float* __restrict__ nodeC, u16* __restrict__ hEx, int* meta)
{
  extern __shared__ char smem[];
  u16*   hst = (u16*)smem;                    // [32][1024] bf16, XOR-swizzled
  float* sG  = (float*)(smem + 65536);        // [4*32][36] gate pre-acts
  const int tid = threadIdx.x;
  const int w = tid >> 6, lane = tid & 63;
  const int g = w & 3, ch = w >> 2;           // gate, col-half (0/1)
  const int l15 = lane & 15, quad = lane >> 4;
  const int n32 = blockIdx.x;                 // owns h-cols n32*32..+32
  int* sflg = meta + MO_SFLG;

  // weights: gate g, cols n32*32 + ch*16 + l15, all k -> 128 persistent VGPRs
  short8 bf[32];
#pragma unroll
  for (int kc = 0; kc < 32; ++kc)
    bf[kc] = cvt8(Whh + ((size_t)(g * 1024 + n32 * 32 + ch * 16 + l15)) * 1024
                  + kc * 32 + quad * 8);

  const int cb = tid >> 4;                    // cell batch (0..31)
  const int cp = tid & 15;                    // cell col-pair (0..15)
  const int c0loc = cp * 2;                   // local col in [0,32)
  const int c0 = n32 * 32 + c0loc;            // global col

  float cst0 = 0.f, cst1 = 0.f;
  for (int t = 0; t < L_; ++t) {
    // prefetch this step's Xg gate inputs (independent of h(t-1))
    float xv[4][2];
    {
      const u16* xr = Xg + (size_t)(cb * 128 + t) * G4_;
#pragma unroll
      for (int gg = 0; gg < 4; ++gg)
#pragma unroll
        for (int u = 0; u < 2; ++u)
          xv[gg][u] = h2f(xr[gg * 1024 + c0 + u]);
    }
    floatx4 acc[2] = {};
    if (t > 0) {
      // stage h(t-1): 8192 u64 agent loads (16/thread, all in flight),
      // chunk order staggered per block -> swizzled LDS
      const unsigned long long* src =
          (const unsigned long long*)(hEx + ((t - 1) & 1) * (B_ * H_));
      unsigned long long tmp[16];
#pragma unroll
      for (int q = 0; q < 16; ++q) {
        int qq = (q + n32) & 15;
        tmp[q] = __hip_atomic_load(src + qq * 512 + tid,
                                   __ATOMIC_RELAXED, __HIP_MEMORY_SCOPE_AGENT);
      }
#pragma unroll
      for (int q = 0; q < 16; ++q) {
        int qq = (q + n32) & 15;
        int idx = qq * 512 + tid;
        int b = idx >> 8, g8 = idx & 255, gr = g8 >> 1;
        *(unsigned long long*)(hst + (b << 10) + ((gr ^ (b & 7)) << 3) + (g8 & 1) * 4) = tmp[q];
      }
      __syncthreads();
#pragma unroll
      for (int kc = 0; kc < 32; ++kc) {       // FULL unroll -> bf[] stays in VGPRs
        int gr = (kc * 4 + quad) ^ (l15 & 7);
        short8 a0 = *(const short8*)(hst + (l15 << 10) + (gr << 3));
        short8 a1 = *(const short8*)(hst + ((16 + l15) << 10) + (gr << 3));
        acc[0] = MFMA(a0, bf[kc], acc[0]);
        acc[1] = MFMA(a1, bf[kc], acc[1]);
      }
    }
#pragma unroll
    for (int mt = 0; mt < 2; ++mt)
#pragma unroll
      for (int r = 0; r < 4; ++r)
        sG[(g * 32 + mt * 16 + quad * 4 + r) * 36 + ch * 16 + l15] = acc[mt][r];
    __syncthreads();
    // cell update: 512 threads = 32 batches x 16 col-pairs
    {
      float cc[2] = { cst0, cst1 };
      float hh[2];
#pragma unroll
      for (int u = 0; u < 2; ++u) {
        int col = c0loc + u;
        float iv = sG[(0 * 32 + cb) * 36 + col] + xv[0][u];
        float fv = sG[(1 * 32 + cb) * 36 + col] + xv[1][u];
        float gv = sG[(2 * 32 + cb) * 36 + col] + xv[2][u];
        float ov = sG[(3 * 32 + cb) * 36 + col] + xv[3][u];
        float c = sigf(fv) * cc[u] + sigf(iv) * tanh_(gv);
        float h = sigf(ov) * tanh_(c);
        cc[u] = c; hh[u] = h;
      }
      cst0 = cc[0]; cst1 = cc[1];
      unsigned pack = (unsigned)f2b(hh[0]) | ((unsigned)f2b(hh[1]) << 16);
      __hip_atomic_store((unsigned*)(hEx + (t & 1) * (B_ * H_)) + (cb << 9) + (c0 >> 1),
                         pack, __ATOMIC_RELAXED, __HIP_MEMORY_SCOPE_AGENT);
      *(unsigned*)(nodeH + (size_t)(cb * 129 + t) * H_ + c0) = pack;   // leaf archive
      *(float2*)(nodeC + (size_t)(cb * 129 + t) * H_ + c0) = make_float2(cc[0], cc[1]);
    }
    __syncthreads();   // drains vmcnt for all waves before flag release
    if (tid == 0)
      __hip_atomic_store(&sflg[n32 * 16], t + 1, __ATOMIC_RELAXED, __HIP_MEMORY_SCOPE_AGENT);
    if (w == 0) {      // wave 0: lanes 0..31 poll one padded line each
      int it = 0;
      for (;;) {
        int v = (lane < 32)
          ? __hip_atomic_load(&sflg[lane * 16], __ATOMIC_RELAXED, __HIP_MEMORY_SCOPE_AGENT)
          : 0x7fffffff;
        if (__all(v >= t + 1) || ++it >= SPIN_CAP) break;
        __builtin_amdgcn_s_sleep(1);
      }
    }
    __syncthreads();
  }
}

// ---------------- K_tree: O(n) Cartesian trees + O(n) level schedule ---------
__global__ void k_tree(const int* __restrict__ words, const int* __restrict__ lens,
                       int* meta)
{
  const int tid = threadIdx.x;
  __shared__ u16 sD[B_][L_];
  __shared__ short sL[B_][L_], sR[B_][L_];     // raw child indices, -1 = none
  __shared__ short sS[B_][130];                // stack (build, then preorder)
  __shared__ short sO[B_][L_];                 // preorder sequence
  __shared__ unsigned char sLev[B_][L_];       // height; 0 = Cartesian leaf
  __shared__ int sHist[132], sCur[132], sMaxLev;
  for (int i = tid; i < 132; i += 256) { sHist[i] = 0; sCur[i] = 0; }
  if (tid == 0) sMaxLev = 1;
  for (int i = tid; i < 256; i += 256) meta[MO_CNT + i] = 0;   // forest flags
  for (int i = tid; i < B_ * L_; i += 256) {   // parallel, coalesced init
    int b = i >> 7, t = i & 127;
    sD[b][t] = (u16)(words[i] % 1000);
    sL[b][t] = -1; sR[b][t] = -1; sLev[b][t] = 0;
  }
  __syncthreads();
  if (tid < B_) {
    const int b = tid;
    int len = lens[b];
    if (len < 2) len = 2;
    if (len > 128) len = 128;
    // --- 1. monotone-stack Cartesian min-tree (ties: leftmost is ancestor) ---
    int sp = 0;
    for (int i = 0; i < len; ++i) {
      int v = sD[b][i];
      int last = -1;
      while (sp > 0) {
        int top = sS[b][sp - 1];
        if ((int)sD[b][top] > v) { last = top; --sp; } else break;
      }
      sL[b][i] = (short)last;                  // last popped = left child of i
      if (sp > 0) sR[b][sS[b][sp - 1]] = (short)i; // i = (current) right child
      sS[b][sp++] = (short)i;
    }
    const int root = sS[b][0];                 // stack bottom = global min
    meta[MO_ROOT + b] = root;
    // --- 2a. preorder via explicit stack ---
    int cnt = 0, tp = 0;
    sS[b][tp++] = (short)root;
    while (tp > 0) {
      int p = sS[b][--tp];
      sO[b][cnt++] = (short)p;
      int l = sL[b][p], r = sR[b][p];
      if (l >= 0) sS[b][tp++] = (short)l;
      if (r >= 0) sS[b][tp++] = (short)r;
    }
    // --- 2b. reverse preorder: children processed before parents ---
    for (int k = cnt - 1; k >= 0; --k) {
      int p = sO[b][k];
      int l = sL[b][p], r = sR[b][p];
      if (l >= 0 || r >= 0) {
        int hl = (l >= 0) ? (int)sLev[b][l] : 0;
        int hr = (r >= 0) ? (int)sLev[b][r] : 0;
        sLev[b][p] = (unsigned char)(1 + (hl > hr ? hl : hr));
      }
    }
    atomicMax(&sMaxLev, (int)sLev[b][root]);
    for (int p = 0; p < len; ++p)
      if (sLev[b][p]) atomicAdd(&sHist[sLev[b][p]], 1);
  }
  __syncthreads();
  if (tid == 0) {
    int off2 = 0;
    for (int r = 1; r <= 128; ++r) {
      meta[MO_LSTART + r] = off2;
      sCur[r] = off2;
      meta[MO_LCOUNT + r] = sHist[r];
      off2 += sHist[r];
    }
    meta[MO_MAXLEV] = sMaxLev;
  }
  __syncthreads();
  if (tid < B_) {
    const int b = tid;
    int len = lens[b];
    if (len < 2) len = 2;
    if (len > 128) len = 128;
    for (int p = 0; p < len; ++p) if (sLev[b][p]) {
      int l = sL[b][p], r = sR[b][p];
      // encode: empty -> 128, Cartesian leaf -> raw index, compose -> 129+idx
      int le = (l < 0) ? 128 : (sLev[b][l] ? 129 + l : l);
      int re = (r < 0) ? 128 : (sLev[b][r] ? 129 + r : r);
      int idx = atomicAdd(&sCur[sLev[b][p]], 1);
      meta[MO_NODES + idx] = (b << 25) | (p << 18) | (le << 9) | re;
    }
  }
}

// ---------------- K_forest: weight-stationary, 4 cols/block, 256 blocks -----
#define FOREST_LDS (147456 + 12288 + 512)     // wlds + sG + sInfo = 160256
__global__ __launch_bounds__(FTHREADS, 2) void k_forest(const u16* __restrict__ Wc,
    const float* __restrict__ bcomp, const u16* __restrict__ nodeH,
    const float* __restrict__ nodeC, u16* __restrict__ compH,
    float* __restrict__ compC, int* meta)
{
  extern __shared__ char smem[];
  u16*   wlds  = (u16*)smem;                       // [384 k-chunks][24 rows][8]
  float* sG    = (float*)(smem + 147456);          // [8 waves][16 nodes][24]
  int*   sInfo = (int*)(smem + 147456 + 12288);    // [128]
  const int bcol = blockIdx.x;                     // owns h-cols 4*bcol..+3
  const int tid = threadIdx.x;
  const int w = tid >> 6, lane = tid & 63;
  const int l15 = lane & 15, quad = lane >> 4;
  int* flg = meta + MO_CNT;                        // [256] per-block progress
  const int maxLev = meta[MO_MAXLEV];

  // ---- stage 24 weight rows into LDS once; LDS addr j*16B linear in tid
  for (int j = tid; j < 9216; j += FTHREADS) {
    int idx = j / 24, r24 = j - idx * 24;          // r24 = gate*4 + col
    int G = (r24 >> 2) * 1024 + bcol * 4 + (r24 & 3);
    *(short8*)(wlds + (size_t)j * 8) = *(const short8*)(Wc + (size_t)G * K3_ + idx * 8);
  }
  __syncthreads();

  for (int rd = 1; rd <= maxLev && rd <= 128; ++rd) {
    const int M = meta[MO_LCOUNT + rd];
    const int base = meta[MO_LSTART + rd];
    const int ntiles = (M + 127) >> 7;
    for (int tile = 0; tile < ntiles; ++tile) {
      __syncthreads();                             // guard sInfo/sG reuse
      if (tid < 128) {
        int j = tile * 128 + tid; if (j >= M) j = M - 1;
        sInfo[tid] = meta[MO_NODES + base + j];
      }
      __syncthreads();
      // --- MFMA: wave w = 16 nodes (lane l15), 2 n-frags (rows 0-15, 16-23)
      {
        int info = sInfo[w * 16 + l15];
        int b = (info >> 25) & 31, p = (info >> 18) & 127;
        int li = (info >> 9) & 0x1FF, ri = info & 0x1FF;
        const u16* A0 = (li <= 128) ? nodeH + ((size_t)(b * 129 + li) << 10)
                                    : compH + ((size_t)(b * 128 + li - 129) << 10);
        const u16* A1 = nodeH + ((size_t)(b * 129 + p) << 10);
        const u16* A2 = (ri <= 128) ? nodeH + ((size_t)(b * 129 + ri) << 10)
                                    : compH + ((size_t)(b * 128 + ri - 129) << 10);
        const u16* Aseg[3] = { A0, A1, A2 };
        floatx4 acc0 = {}, acc1 = {};
#pragma unroll
        for (int seg = 0; seg < 3; ++seg) {
          const u16* Ap = Aseg[seg] + quad * 8;
          const u16* B0 = wlds + ((size_t)((seg * 128 + quad) * 24 + l15)) * 8;
          const u16* B1 = wlds + ((size_t)((seg * 128 + quad) * 24 + 16 + (l15 & 7))) * 8;
#pragma unroll 4
          for (int kcL = 0; kcL < 32; ++kcL) {
            short8 av = *(const short8*)(Ap + kcL * 32);
            acc0 = MFMA(av, *(const short8*)(B0 + kcL * 768), acc0);
            acc1 = MFMA(av, *(const short8*)(B1 + kcL * 768), acc1);
          }
        }
        // D[m=quad*4+r][n=l15]; frag1 rows 16-23 valid only for l15<8
        float* sgw = sG + w * 384;
#pragma unroll
        for (int r = 0; r < 4; ++r)
          sgw[(quad * 4 + r) * 24 + l15] = acc0[r];
        if (l15 < 8)
#pragma unroll
          for (int r = 0; r < 4; ++r)
            sgw[(quad * 4 + r) * 24 + 16 + l15] = acc1[r];
      }
      __syncthreads();
      // --- epilogue: 512 threads = 128 nodes x 4 cols (block-local gates) --
      {
        int j_loc = tid >> 2, c = tid & 3;
        int j = tile * 128 + j_loc;
        if (j < M) {
          int info = sInfo[j_loc];
          int b = (info >> 25) & 31, p = (info >> 18) & 127;
          int li = (info >> 9) & 0x1FF, ri = info & 0x1FF;
          int hc = bcol * 4 + c;
          const float* gq = sG + (j_loc >> 4) * 384 + (j_loc & 15) * 24 + c;
          float gi  = gq[0]  + bcomp[hc];
          float gfl = gq[4]  + bcomp[H_ + hc];
          float gfx = gq[8]  + bcomp[2 * H_ + hc];
          float gfr = gq[12] + bcomp[3 * H_ + hc];
          float gu  = gq[16] + bcomp[4 * H_ + hc];
          float go  = gq[20] + bcomp[5 * H_ + hc];
          float cl  = (li <= 128) ? nodeC[(size_t)(b * 129 + li) * H_ + hc]
                                  : compC[(size_t)(b * 128 + li - 129) * H_ + hc];
          float cx  = nodeC[(size_t)(b * 129 + p) * H_ + hc];
          float cr2 = (ri <= 128) ? nodeC[(size_t)(b * 129 + ri) * H_ + hc]
                                  : compC[(size_t)(b * 128 + ri - 129) * H_ + hc];
          float cc = sigf(gi) * tanh_(gu) + sigf(gfl) * cl + sigf(gfx) * cx + sigf(gfr) * cr2;
          float hh = sigf(go) * tanh_(cc);
          __hip_atomic_store(&compH[(size_t)(b * 128 + p) * H_ + hc], f2b(hh),
                             __ATOMIC_RELAXED, __HIP_MEMORY_SCOPE_AGENT);
          compC[(size_t)(b * 128 + p) * H_ + hc] = cc;   // block-private cols
        }
      }
    }
    // ---- level barrier: contention-free flags (k_scan pattern, 256 blocks)
    __syncthreads();               // drains vmcnt for all waves before release
    if (tid == 0)
      __hip_atomic_store(&flg[bcol], rd, __ATOMIC_RELAXED, __HIP_MEMORY_SCOPE_AGENT);
    if (w == 0) {                  // wave 0: 4 flags per lane, ballot
      int it = 0;
      for (;;) {
        int f0 = __hip_atomic_load(&flg[lane],       __ATOMIC_RELAXED, __HIP_MEMORY_SCOPE_AGENT);
        int f1 = __hip_atomic_load(&flg[lane + 64],  __ATOMIC_RELAXED, __HIP_MEMORY_SCOPE_AGENT);
        int f2 = __hip_atomic_load(&flg[lane + 128], __ATOMIC_RELAXED, __HIP_MEMORY_SCOPE_AGENT);
        int f3 = __hip_atomic_load(&flg[lane + 192], __ATOMIC_RELAXED, __HIP_MEMORY_SCOPE_AGENT);
        bool ok = (f0 >= rd) && (f1 >= rd) && (f2 >= rd) && (f3 >= rd);
        if (__all(ok) || ++it >= SPIN_CAP2) break;
        __builtin_amdgcn_s_sleep(1);
      }
    }
    __syncthreads();
  }
}

// ---------------- K_round: fallback path (f32 weights, per-level dispatch) ---
template<int BF16B>
__global__ __launch_bounds__(384) void k_round(const void* __restrict__ Wc,
    const float* __restrict__ bcomp, const u16* __restrict__ nodeH,
    const float* __restrict__ nodeC, u16* __restrict__ compH,
    float* __restrict__ compC, const int* __restrict__ meta, int rd)
{
  const int M = meta[MO_LCOUNT + rd];
  if (M <= 0 || M > 2048) return;
  const int mb = blockIdx.x >> 6, hs = blockIdx.x & 63;
  if (mb * 64 >= M) return;
  const int base = meta[MO_LSTART + rd];
  const int tid = threadIdx.x;
  const int w = tid >> 6, lane = tid & 63;
  const int l15 = lane & 15, quad = lane >> 4;
  __shared__ float sG[6][64][17];
  __shared__ int sInfo[64];
  if (tid < 64) {
    int j = mb * 64 + tid; if (j >= M) j = M - 1;
    sInfo[tid] = meta[MO_NODES + base + j];
  }
  __syncthreads();
  {
    const u16* aseg[3][4];
#pragma unroll
    for (int mi = 0; mi < 4; ++mi) {
      int info = sInfo[mi * 16 + l15];
      int b = (info >> 25) & 31, p = (info >> 18) & 127;
      int li = (info >> 9) & 0x1FF, ri = info & 0x1FF;
      aseg[0][mi] = (li <= 128) ? nodeH + ((size_t)(b * 129 + li) << 10)
                                : compH + ((size_t)(b * 128 + li - 129) << 10);
      aseg[1][mi] = nodeH + ((size_t)(b * 129 + p) << 10);
      aseg[2][mi] = (ri <= 128) ? nodeH + ((size_t)(b * 129 + ri) << 10)
                                : compH + ((size_t)(b * 128 + ri - 129) << 10);
    }
    floatx4 acc[4] = {};
    const size_t brow = (size_t)(w * 1024 + hs * 16 + l15) * K3_;
    for (int kc = 0; kc < 96; ++kc) {
      int seg = kc >> 5, ko = (kc & 31) * 32 + quad * 8;
      short8 bfr;
      if (BF16B) bfr = *(const short8*)((const u16*)Wc + brow + kc * 32 + quad * 8);
      else       bfr = cvt8((const float*)Wc + brow + kc * 32 + quad * 8);
      acc[0] = MFMA(*(const short8*)(aseg[seg][0] + ko), bfr, acc[0]);
      acc[1] = MFMA(*(const short8*)(aseg[seg][1] + ko), bfr, acc[1]);
      acc[2] = MFMA(*(const short8*)(aseg[seg][2] + ko), bfr, acc[2]);
      acc[3] = MFMA(*(const short8*)(aseg[seg][3] + ko), bfr, acc[3]);
    }
#pragma unroll
    for (int mi = 0; mi < 4; ++mi)
#pragma unroll
      for (int r = 0; r < 4; ++r) sG[w][mi * 16 + quad * 4 + r][l15] = acc[mi][r];
  }
  __syncthreads();
  for (int idx = tid; idx < 1024; idx += 384) {
    int j_loc = idx >> 4, col = idx & 15;
    int j = mb * 64 + j_loc;
    if (j < M) {
      int info = sInfo[j_loc];
      int b = (info >> 25) & 31, p = (info >> 18) & 127;
      int li = (info >> 9) & 0x1FF, ri = info & 0x1FF;
      int hc = hs * 16 + col;
      float gi  = sG[0][j_loc][col] + bcomp[hc];
      float gfl = sG[1][j_loc][col] + bcomp[H_ + hc];
      float gfx = sG[2][j_loc][col] + bcomp[2 * H_ + hc];
      float gfr = sG[3][j_loc][col] + bcomp[3 * H_ + hc];
      float gu  = sG[4][j_loc][col] + bcomp[4 * H_ + hc];
      float go  = sG[5][j_loc][col] + bcomp[5 * H_ + hc];
      float cl  = (li <= 128) ? nodeC[(size_t)(b * 129 + li) * H_ + hc]
                              : compC[(size_t)(b * 128 + li - 129) * H_ + hc];
      float cx  = nodeC[(size_t)(b * 129 + p) * H_ + hc];
      float cr2 = (ri <= 128) ? nodeC[(size_t)(b * 129 + ri) * H_ + hc]
                              : compC[(size_t)(b * 128 + ri - 129) * H_ + hc];
      float c = sigf(gi) * tanh_(gu) + sigf(gfl) * cl + sigf(gfx) * cx + sigf(gfr) * cr2;
      float h = sigf(go) * tanh_(c);
      compH[(size_t)(b * 128 + p) * H_ + hc] = f2b(h);
      compC[(size_t)(b * 128 + p) * H_ + hc] = c;
    }
  }
}

// ---------------- K_out: emit root h then root c (f32) -----------------------
__global__ void k_out(const u16* __restrict__ compH, const float* __restrict__ compC,
                      const int* __restrict__ meta, float* __restrict__ out)
{
  int i = blockIdx.x * 256 + threadIdx.x;
  if (i >= 2 * B_ * H_) return;
  int part = i >> 15;
  int b = (i >> 10) & 31;
  int c = i & 1023;
  int root = meta[MO_ROOT + b] & 127;
  size_t rw = (size_t)(b * 128 + root) * H_ + c;
  out[i] = part ? compC[rw] : b2f(compH[rw]);
}

extern "C" void kernel_launch(void* const* d_in, const int* in_sizes, int n_in,
                              void* d_out, int out_size, void* d_ws, size_t ws_size,
                              hipStream_t stream)
{
  (void)in_sizes; (void)n_in; (void)out_size;
  const float* emb   = (const float*)d_in[0];
  const float* Wih   = (const float*)d_in[1];
  const float* Whh   = (const float*)d_in[2];
  const float* bih   = (const float*)d_in[3];
  const float* bhh   = (const float*)d_in[4];
  const float* Wcomp = (const float*)d_in[5];
  const float* bcomp = (const float*)d_in[6];
  const int* words   = (const int*)d_in[7];
  const int* lens    = (const int*)d_in[8];

  char* ws = (char*)d_ws;
  size_t off = 0;
  auto take = [&](size_t bytes) -> void* {
    void* p = ws + off; off += (bytes + 255) & ~(size_t)255; return p;
  };
  int*   meta  = (int*)  take((size_t)(512 + 4096 + 256 + 512) * 4); // control
  u16*   nodeH = (u16*)  take((size_t)B_ * 129 * H_ * 2);     // leaves + zero row
  float* nodeC = (float*)take((size_t)B_ * 129 * H_ * 4);
  u16*   embP  = (u16*)  take((size_t)B_ * L_ * DP_ * 2);
  u16*   WihP  = (u16*)  take((size_t)G4_ * DP_ * 2);
  u16*   hEx   = (u16*)  take((size_t)2 * B_ * H_ * 2);       // coherent h dbuf
  char*  xgreg = (char*) take((size_t)B_ * L_ * G4_ * 2);     // 33.5 MB
  u16*   Xg    = (u16*)  xgreg;
  u16*   compH = (u16*)  xgreg;                               // alias: dead Xg
  float* compC = (float*)(xgreg + (size_t)B_ * 128 * H_ * 2);
  // optional pre-converted bf16 Wcomp (37.75 MB) - only if ws has room
  u16* WcompB = nullptr;
  if (off + (size_t)6 * H_ * K3_ * 2 <= ws_size)
    WcompB = (u16*)take((size_t)6 * H_ * K3_ * 2);

  hipFuncSetAttribute((const void*)k_scan,
                      hipFuncAttributeMaxDynamicSharedMemorySize, SCAN_LDS);
  hipFuncSetAttribute((const void*)k_forest,
                      hipFuncAttributeMaxDynamicSharedMemorySize, FOREST_LDS);

  k_init<<<dim3(2048), dim3(256), 0, stream>>>(emb, Wih, Wcomp, embP, WihP,
                                               WcompB, nodeH, nodeC, meta);
  k_xg  <<<dim3(2048), dim3(256), 0, stream>>>(embP, WihP, bih, bhh, Xg);
  k_scan<<<dim3(32), dim3(512), SCAN_LDS, stream>>>(Whh, Xg, nodeH, nodeC, hEx, meta);
  k_tree<<<dim3(1), dim3(256), 0, stream>>>(words, lens, meta);
  if (WcompB) {
    k_forest<<<dim3(FGRID), dim3(FTHREADS), FOREST_LDS, stream>>>(WcompB, bcomp,
                                                nodeH, nodeC, compH, compC, meta);
  } else {
    for (int rd = 1; rd <= NROUNDS; ++rd) {
      int maxM = 32 * 128 / (rd + 1);
      if (maxM > 2048) maxM = 2048;
      int nb = ((maxM + 63) / 64) * 64;
      k_round<0><<<dim3(nb), dim3(384), 0, stream>>>(Wcomp, bcomp, nodeH, nodeC,
                                                     compH, compC, meta, rd);
    }
  }
  k_out<<<dim3(256), dim3(256), 0, stream>>>(compH, compC, meta, (float*)d_out);
}